// Round 6
// baseline (954.427 us; speedup 1.0000x reference)
//
#include <hip/hip_runtime.h>
#include <hip/hip_bf16.h>
#include <math.h>

typedef __hip_bfloat16 bf16;
typedef __attribute__((ext_vector_type(8))) short bf16x8;
typedef __attribute__((ext_vector_type(4))) float f32x4;

#define DIMX 1536
#define NSEQ 4096
#define NHEAD 8
#define DKH 64
#define DVH 192
#define HDK 512
#define HDV 1536

static __device__ __forceinline__ float b2f(bf16 x){ return __bfloat162float(x); }
static __device__ __forceinline__ bf16 f2b(float x){ return __float2bfloat16(x); }

#define GLD_TO_LDS(gsrc, ldst) __builtin_amdgcn_global_load_lds( \
    (const __attribute__((address_space(1))) unsigned int*)(gsrc), \
    (__attribute__((address_space(3))) unsigned int*)(ldst), 16, 0, 0)

// ---------------- LUT: g(|d|) = first f in [0,16) with cw[f] > |d| ----------------
__global__ void k_lut(unsigned char* __restrict__ lut){
  int d = blockIdx.x*256 + threadIdx.x;
  if (d >= NSEQ) return;
  int g = 15;
  #pragma unroll
  for (int f=15; f>=0; --f){
    float cw = (float)exp(log(4097.0)*((double)(f+1)/16.0));
    if (cw > (float)d) g = f;
  }
  lut[d] = (unsigned char)g;
}

// ---------------- convert fp32 (K,N) -> bf16 (N,K), single ----------------
__global__ __launch_bounds__(256) void k_cvtT(const float* __restrict__ W, bf16* __restrict__ WT, int K, int N){
  __shared__ float t[32][33];
  int n0 = blockIdx.x<<5, k0 = blockIdx.y<<5;
  int tx = threadIdx.x & 31, ty = threadIdx.x >> 5;
  #pragma unroll
  for (int r=ty; r<32; r+=8) t[r][tx] = W[(size_t)(k0+r)*N + n0 + tx];
  __syncthreads();
  #pragma unroll
  for (int r=ty; r<32; r+=8) WT[(size_t)(n0+r)*K + k0 + tx] = f2b(t[tx][r]);
}

// ---------------- convert fp32 (K,N) -> bf16 hi/lo (N,K) ----------------
__global__ __launch_bounds__(256) void k_cvtT2(const float* __restrict__ W, bf16* __restrict__ WTh,
                                               bf16* __restrict__ WTl, int K, int N){
  __shared__ float t[32][33];
  int n0 = blockIdx.x<<5, k0 = blockIdx.y<<5;
  int tx = threadIdx.x & 31, ty = threadIdx.x >> 5;
  #pragma unroll
  for (int r=ty; r<32; r+=8) t[r][tx] = W[(size_t)(k0+r)*N + n0 + tx];
  __syncthreads();
  #pragma unroll
  for (int r=ty; r<32; r+=8){
    float v = t[tx][r];
    bf16 hi = f2b(v);
    WTh[(size_t)(n0+r)*K + k0 + tx] = hi;
    WTl[(size_t)(n0+r)*K + k0 + tx] = f2b(v - b2f(hi));
  }
}

// ---------------- bf16 transpose (R,C) -> (C,R) ----------------
__global__ __launch_bounds__(256) void k_T(const bf16* __restrict__ src, bf16* __restrict__ dst, int R, int C){
  __shared__ bf16 t[64][65];
  int c0 = blockIdx.x<<6, r0 = blockIdx.y<<6;
  int tx = threadIdx.x & 63, ty = threadIdx.x >> 6;
  for (int r=ty; r<64; r+=4) t[r][tx] = src[(size_t)(r0+r)*C + c0 + tx];
  __syncthreads();
  for (int r=ty; r<64; r+=4) dst[(size_t)(c0+r)*R + r0 + tx] = t[tx][r];
}

// ---------------- LayerNorm -> bf16 hi/lo ----------------
__global__ __launch_bounds__(256) void k_ln(const float* __restrict__ x, const float* __restrict__ g,
                                            const float* __restrict__ b,
                                            bf16* __restrict__ xnh, bf16* __restrict__ xnl){
  int row = blockIdx.x, t = threadIdx.x;
  const float* xr = x + (size_t)row*DIMX;
  float v[6]; float s=0.f, ss=0.f;
  #pragma unroll
  for (int j=0;j<6;++j){ v[j]=xr[t+256*j]; s+=v[j]; ss+=v[j]*v[j]; }
  int lane = t&63, wave = t>>6;
  #pragma unroll
  for (int off=32; off>0; off>>=1){ s += __shfl_down(s,off,64); ss += __shfl_down(ss,off,64); }
  __shared__ float red[8];
  if (lane==0){ red[wave]=s; red[wave+4]=ss; }
  __syncthreads();
  s = red[0]+red[1]+red[2]+red[3];
  ss = red[4]+red[5]+red[6]+red[7];
  float mu = s*(1.f/DIMX);
  float var = ss*(1.f/DIMX) - mu*mu;
  float rstd = rsqrtf(var + 1e-3f);
  #pragma unroll
  for (int j=0;j<6;++j){
    int c = t+256*j;
    float xv = (v[j]-mu)*rstd*g[c] + b[c];
    bf16 hi = f2b(xv);
    xnh[(size_t)row*DIMX + c] = hi;
    xnl[(size_t)row*DIMX + c] = f2b(xv - b2f(hi));
  }
}

// ---------------- generic bf16 MFMA GEMM: C(M,N) = A(M,K) @ BT(N,K)^T ----------------
template<int EPI>
__global__ __launch_bounds__(256) void k_gemm(const bf16* __restrict__ A, const bf16* __restrict__ BT,
    void* __restrict__ Cout, const float* __restrict__ bias, int M, int N, int K)
{
  __shared__ bf16 As[128][32];
  __shared__ bf16 Bs[128][32];
  int nbx = N>>7;
  int m0 = (blockIdx.x / nbx)<<7, n0 = (blockIdx.x % nbx)<<7;
  int tid = threadIdx.x, wave = tid>>6, lane = tid&63;
  int lr = lane&15, lc = lane>>4;
  int wm = (wave>>1)<<6, wn = (wave&1)<<6;
  f32x4 acc[4][4] = {};
  for (int k0=0; k0<K; k0+=32){
    __syncthreads();
    #pragma unroll
    for (int it=0; it<2; ++it){
      int id = tid + (it<<8);
      int rr = id>>2, cc = id&3;
      unsigned wbase = (unsigned)(((it<<8) + (tid & 192))*16);
      GLD_TO_LDS(A  + (size_t)(m0+rr)*K + k0 + cc*8, (char*)As + wbase);
      GLD_TO_LDS(BT + (size_t)(n0+rr)*K + k0 + cc*8, (char*)Bs + wbase);
    }
    __syncthreads();
    bf16x8 af[4], bfr[4];
    #pragma unroll
    for (int mt=0; mt<4; ++mt) af[mt] = *(const bf16x8*)(&As[wm + mt*16 + lr][lc*8]);
    #pragma unroll
    for (int nt=0; nt<4; ++nt) bfr[nt] = *(const bf16x8*)(&Bs[wn + nt*16 + lr][lc*8]);
    #pragma unroll
    for (int mt=0; mt<4; ++mt)
      #pragma unroll
      for (int nt=0; nt<4; ++nt)
        acc[mt][nt] = __builtin_amdgcn_mfma_f32_16x16x32_bf16(af[mt], bfr[nt], acc[mt][nt], 0,0,0);
  }
  #pragma unroll
  for (int mt=0; mt<4; ++mt){
    #pragma unroll
    for (int nt=0; nt<4; ++nt){
      #pragma unroll
      for (int reg=0; reg<4; ++reg){
        int row = m0 + wm + mt*16 + (lc<<2) + reg;
        int col = n0 + wn + nt*16 + lr;
        if (EPI==0) ((bf16*)Cout)[(size_t)row*N + col] = f2b(acc[mt][nt][reg]);
        else        ((float*)Cout)[(size_t)row*N + col] = acc[mt][nt][reg] + bias[col];
      }
    }
  }
}

// ---------------- split (compensated) GEMM: fp32-accurate C = A @ BT^T ----------------
template<int EPIQ>
__global__ __launch_bounds__(256) void k_gemm3(const bf16* __restrict__ Ahi, const bf16* __restrict__ Alo,
    const bf16* __restrict__ Bhi, const bf16* __restrict__ Blo,
    bf16* __restrict__ Ohi, bf16* __restrict__ Olo,
    const float* __restrict__ cb, int M, int N, int K)
{
  __shared__ bf16 Ash[128][32];
  __shared__ bf16 Asl[128][32];
  __shared__ bf16 Bsh[128][32];
  __shared__ bf16 Bsl[128][32];
  int nbx = N>>7;
  int m0 = (blockIdx.x / nbx)<<7, n0 = (blockIdx.x % nbx)<<7;
  int tid = threadIdx.x, wave = tid>>6, lane = tid&63;
  int lr = lane&15, lc = lane>>4;
  int wm = (wave>>1)<<6, wn = (wave&1)<<6;
  f32x4 acc[4][4] = {};
  for (int k0=0; k0<K; k0+=32){
    __syncthreads();
    #pragma unroll
    for (int it=0; it<2; ++it){
      int id = tid + (it<<8);
      int rr = id>>2, cc = id&3;
      unsigned wbase = (unsigned)(((it<<8) + (tid & 192))*16);
      size_t ga = (size_t)(m0+rr)*K + k0 + cc*8;
      size_t gb = (size_t)(n0+rr)*K + k0 + cc*8;
      GLD_TO_LDS(Ahi + ga, (char*)Ash + wbase);
      GLD_TO_LDS(Alo + ga, (char*)Asl + wbase);
      GLD_TO_LDS(Bhi + gb, (char*)Bsh + wbase);
      GLD_TO_LDS(Blo + gb, (char*)Bsl + wbase);
    }
    __syncthreads();
    bf16x8 ah[4], al[4], bh[4], bl[4];
    #pragma unroll
    for (int mt=0; mt<4; ++mt){
      ah[mt] = *(const bf16x8*)(&Ash[wm + mt*16 + lr][lc*8]);
      al[mt] = *(const bf16x8*)(&Asl[wm + mt*16 + lr][lc*8]);
    }
    #pragma unroll
    for (int nt=0; nt<4; ++nt){
      bh[nt] = *(const bf16x8*)(&Bsh[wn + nt*16 + lr][lc*8]);
      bl[nt] = *(const bf16x8*)(&Bsl[wn + nt*16 + lr][lc*8]);
    }
    #pragma unroll
    for (int mt=0; mt<4; ++mt)
      #pragma unroll
      for (int nt=0; nt<4; ++nt){
        acc[mt][nt] = __builtin_amdgcn_mfma_f32_16x16x32_bf16(ah[mt], bh[nt], acc[mt][nt], 0,0,0);
        acc[mt][nt] = __builtin_amdgcn_mfma_f32_16x16x32_bf16(al[mt], bh[nt], acc[mt][nt], 0,0,0);
        acc[mt][nt] = __builtin_amdgcn_mfma_f32_16x16x32_bf16(ah[mt], bl[nt], acc[mt][nt], 0,0,0);
      }
  }
  #pragma unroll
  for (int mt=0; mt<4; ++mt){
    #pragma unroll
    for (int nt=0; nt<4; ++nt){
      #pragma unroll
      for (int reg=0; reg<4; ++reg){
        int row = m0 + wm + mt*16 + (lc<<2) + reg;
        int col = n0 + wn + nt*16 + lr;
        float v = acc[mt][nt][reg];
        if (EPIQ==1) v = v*0.125f + cb[col & (HDK-1)];
        bf16 hi = f2b(v);
        Ohi[(size_t)row*N + col] = hi;
        Olo[(size_t)row*N + col] = f2b(v - b2f(hi));
      }
    }
  }
}

// ---------------- per (h,i): u = Wr_h^T (qp - cb + pb), suffix sums A/B ----------------
__global__ __launch_bounds__(64) void k_abtab(const bf16* __restrict__ qph, const bf16* __restrict__ qpl,
                                              const float* __restrict__ Wr,
                                              const float* __restrict__ cb, const float* __restrict__ pb,
                                              float* __restrict__ ab){
  int i = blockIdx.x, h = blockIdx.y;
  int lane = threadIdx.x;
  __shared__ float qpp[64];
  __shared__ float us[32];
  size_t qi = (size_t)i*HDK + h*DKH + lane;
  int col = h*DKH + lane;
  qpp[lane] = b2f(qph[qi]) + b2f(qpl[qi]) - cb[col] + pb[col];
  __syncthreads();
  if (lane < 32){
    const float* wr = Wr + (size_t)lane*HDK + h*DKH;
    float u=0.f;
    #pragma unroll
    for (int d2=0; d2<64; ++d2) u += wr[d2]*qpp[d2];
    us[lane]=u;
  }
  __syncthreads();
  if (lane < 16){
    float a=0.f, bb=0.f;
    for (int f=15; f>=lane; --f){ a += us[f]; bb += us[16+f]; }
    float* o = ab + ((size_t)h*NSEQ + i)*32;
    o[lane]=a; o[16+lane]=bb;
  }
}

// ---------------- flash attention: K/V read direct from L2 (head pinned to XCD), barrier-free loop ----------------
__global__ __launch_bounds__(256,3) void k_attn(
    const bf16* __restrict__ qph, const bf16* __restrict__ qpl,
    const bf16* __restrict__ kh_rm, const bf16* __restrict__ kl_rm,
    const bf16* __restrict__ vt, const float* __restrict__ ab,
    const unsigned char* __restrict__ lut, bf16* __restrict__ O)
{
  int wg = blockIdx.x;
  int h  = wg & 7;          // consecutive wgids round-robin XCDs -> head pinned to one XCD's L2 (K/V slice 2.5MB < 4MB)
  int q0 = (wg >> 3) * 64;
  int tid = threadIdx.x, wave = tid>>6, lane = tid&63;
  int lr = lane&15, lc = lane>>4;

  __shared__ bf16 Ps[4][16][64];   // per-wave P [qrow][kv], swizzled (intra-wave only, no barrier)
  __shared__ float2 ABs[64][17];   // (sym,asy) suffix tables; pad 17 avoids bank aliasing
  __shared__ unsigned char luts[4096];

  for (int xx=tid; xx<1024; xx+=256){
    int row = xx>>4, g = xx&15;
    const float* src = ab + ((size_t)h*NSEQ + q0 + row)*32;
    ABs[row][g] = make_float2(src[g], src[16+g]);
  }
  for (int xx=tid; xx<4096; xx+=256) luts[xx] = lut[xx];

  bf16x8 qfh[2], qfl[2];
  {
    int row = q0 + wave*16 + lr;
    const bf16* qrh = qph + (size_t)row*HDK + h*DKH;
    const bf16* qrl = qpl + (size_t)row*HDK + h*DKH;
    qfh[0] = *(const bf16x8*)(qrh + 8*lc);
    qfh[1] = *(const bf16x8*)(qrh + 32 + 8*lc);
    qfl[0] = *(const bf16x8*)(qrl + 8*lc);
    qfl[1] = *(const bf16x8*)(qrl + 32 + 8*lc);
  }
  __syncthreads();   // ABs/luts visible; the ONLY block-wide barrier

  const bf16* Kh = kh_rm + h*DKH;
  const bf16* Kl = kl_rm + h*DKH;
  const bf16* Vt = vt + (size_t)h*DVH*NSEQ;

  f32x4 oacc[12] = {};
  float mrow[4], lrow[4];
  #pragma unroll
  for (int r=0;r<4;++r){ mrow[r]=-3e38f; lrow[r]=0.f; }

  for (int kv0=0; kv0<NSEQ; kv0+=64) {
    // S = Q K^T (16 q-rows per wave x 64 keys), compensated; K frags straight from L2
    f32x4 sf[4];
    #pragma unroll
    for (int ct=0; ct<4; ++ct){
      f32x4 s = {};
      const bf16* krh = Kh + (size_t)(kv0 + ct*16 + lr)*HDK + 8*lc;
      const bf16* krl = Kl + (size_t)(kv0 + ct*16 + lr)*HDK + 8*lc;
      bf16x8 kh0 = *(const bf16x8*)(krh);
      bf16x8 kh1 = *(const bf16x8*)(krh + 32);
      bf16x8 kl0 = *(const bf16x8*)(krl);
      bf16x8 kl1 = *(const bf16x8*)(krl + 32);
      s = __builtin_amdgcn_mfma_f32_16x16x32_bf16(qfh[0], kh0, s, 0,0,0);
      s = __builtin_amdgcn_mfma_f32_16x16x32_bf16(qfh[1], kh1, s, 0,0,0);
      s = __builtin_amdgcn_mfma_f32_16x16x32_bf16(qfl[0], kh0, s, 0,0,0);
      s = __builtin_amdgcn_mfma_f32_16x16x32_bf16(qfl[1], kh1, s, 0,0,0);
      s = __builtin_amdgcn_mfma_f32_16x16x32_bf16(qfh[0], kl0, s, 0,0,0);
      s = __builtin_amdgcn_mfma_f32_16x16x32_bf16(qfh[1], kl1, s, 0,0,0);
      sf[ct]=s;
    }
    // decomposed relative-position bias; track new max
    float mnew[4];
    #pragma unroll
    for (int r=0;r<4;++r) mnew[r]=mrow[r];
    #pragma unroll
    for (int ct=0; ct<4; ++ct){
      int j = kv0 + ct*16 + lr;
      #pragma unroll
      for (int reg=0; reg<4; ++reg){
        int rowloc = wave*16 + 4*lc + reg;
        int dd = j - (q0 + rowloc);
        int ad = dd<0 ? -dd : dd;
        int gg = luts[ad];
        float2 sb = ABs[rowloc][gg];
        float bias = sb.x + (dd>0 ? sb.y : (dd<0 ? -sb.y : 0.f));
        float sv = sf[ct][reg] + bias;
        sf[ct][reg] = sv;
        mnew[reg] = fmaxf(mnew[reg], sv);
      }
    }
    #pragma unroll
    for (int off=1; off<16; off<<=1){
      #pragma unroll
      for (int r=0;r<4;++r) mnew[r] = fmaxf(mnew[r], __shfl_xor(mnew[r], off, 64));
    }
    float scl[4];
    #pragma unroll
    for (int r=0;r<4;++r){
      scl[r] = __expf(mrow[r]-mnew[r]);
      mrow[r]=mnew[r];
      lrow[r]*=scl[r];
    }
    #pragma unroll
    for (int ct=0; ct<4; ++ct){
      #pragma unroll
      for (int reg=0; reg<4; ++reg){
        float p = __expf(sf[ct][reg]-mrow[reg]);
        lrow[reg]+=p;
        int prow = 4*lc+reg, pcol = ct*16+lr;
        Ps[wave][prow][((pcol>>3) ^ (prow&7))*8 + (pcol&7)] = f2b(p);
      }
    }
    #pragma unroll
    for (int t12=0;t12<12;++t12){
      #pragma unroll
      for (int reg=0;reg<4;++reg) oacc[t12][reg]*=scl[reg];
    }
    bf16x8 pa[2];
    #pragma unroll
    for (int kk=0; kk<2; ++kk)
      pa[kk] = *(const bf16x8*)(&Ps[wave][lr][((kk*4+lc) ^ (lr&7))*8]);
    // PV: V frags straight from L2
    #pragma unroll
    for (int t12=0; t12<12; ++t12){
      const bf16* vr = Vt + (size_t)(t12*16 + lr)*NSEQ + kv0 + 8*lc;
      bf16x8 v0 = *(const bf16x8*)(vr);
      bf16x8 v1 = *(const bf16x8*)(vr + 32);
      oacc[t12] = __builtin_amdgcn_mfma_f32_16x16x32_bf16(pa[0], v0, oacc[t12], 0,0,0);
      oacc[t12] = __builtin_amdgcn_mfma_f32_16x16x32_bf16(pa[1], v1, oacc[t12], 0,0,0);
    }
  }
  #pragma unroll
  for (int off=1; off<16; off<<=1){
    #pragma unroll
    for (int r=0;r<4;++r) lrow[r] += __shfl_xor(lrow[r], off, 64);
  }
  float rin[4];
  #pragma unroll
  for (int r=0;r<4;++r) rin[r] = 1.f/lrow[r];
  #pragma unroll
  for (int t12=0;t12<12;++t12){
    #pragma unroll
    for (int reg=0;reg<4;++reg){
      int row = q0 + wave*16 + 4*lc + reg;
      O[(size_t)row*HDV + h*DVH + t12*16 + lr] = f2b(oacc[t12][reg]*rin[reg]);
    }
  }
}

extern "C" void kernel_launch(void* const* d_in, const int* in_sizes, int n_in,
                              void* d_out, int out_size, void* d_ws, size_t ws_size,
                              hipStream_t stream) {
  const float* x  = (const float*)d_in[0];
  const float* lg = (const float*)d_in[1];
  const float* lb = (const float*)d_in[2];
  const float* Wq = (const float*)d_in[3];
  const float* Wk = (const float*)d_in[4];
  const float* Wv = (const float*)d_in[5];
  const float* Wr = (const float*)d_in[6];
  const float* Wo = (const float*)d_in[7];
  const float* bo = (const float*)d_in[8];
  const float* cb = (const float*)d_in[9];
  const float* pb = (const float*)d_in[10];
  float* out = (float*)d_out;

  char* ws = (char*)d_ws;
  size_t off = 0;
  auto alloc = [&](size_t bytes)->void*{ void* p = ws + off; off += (bytes + 255) & ~(size_t)255; return p; };
  bf16* WqTh = (bf16*)alloc((size_t)HDK*DIMX*2);
  bf16* WqTl = (bf16*)alloc((size_t)HDK*DIMX*2);
  bf16* WkTh = (bf16*)alloc((size_t)HDK*DIMX*2);
  bf16* WkTl = (bf16*)alloc((size_t)HDK*DIMX*2);
  bf16* WvT  = (bf16*)alloc((size_t)HDV*DIMX*2);
  bf16* WoT  = (bf16*)alloc((size_t)DIMX*HDV*2);
  bf16* xnh  = (bf16*)alloc((size_t)NSEQ*DIMX*2);
  bf16* xnl  = (bf16*)alloc((size_t)NSEQ*DIMX*2);
  bf16* qph  = (bf16*)alloc((size_t)NSEQ*HDK*2);
  bf16* qpl  = (bf16*)alloc((size_t)NSEQ*HDK*2);
  bf16* kh   = (bf16*)alloc((size_t)NSEQ*HDK*2);
  bf16* kl   = (bf16*)alloc((size_t)NSEQ*HDK*2);
  bf16* v_rm = (bf16*)alloc((size_t)NSEQ*HDV*2);
  bf16* vt   = (bf16*)alloc((size_t)HDV*NSEQ*2);
  float* ab  = (float*)alloc((size_t)NHEAD*NSEQ*32*4);
  bf16* Obuf = (bf16*)alloc((size_t)NSEQ*HDV*2);
  unsigned char* lut = (unsigned char*)alloc(NSEQ);
  (void)in_sizes; (void)n_in; (void)out_size; (void)ws_size;

  k_cvtT2<<<dim3(HDK/32,  DIMX/32), 256, 0, stream>>>(Wq, WqTh, WqTl, DIMX, HDK);
  k_cvtT2<<<dim3(HDK/32,  DIMX/32), 256, 0, stream>>>(Wk, WkTh, WkTl, DIMX, HDK);
  k_cvtT <<<dim3(HDV/32,  DIMX/32), 256, 0, stream>>>(Wv, WvT, DIMX, HDV);
  k_cvtT <<<dim3(DIMX/32, HDV/32),  256, 0, stream>>>(Wo, WoT, HDV, DIMX);
  k_lut<<<16, 256, 0, stream>>>(lut);
  k_ln<<<NSEQ, 256, 0, stream>>>(x, lg, lb, xnh, xnl);

  k_gemm3<1><<<(NSEQ/128)*(HDK/128), 256, 0, stream>>>(xnh, xnl, WqTh, WqTl, qph, qpl, cb, NSEQ, HDK, DIMX);
  k_gemm3<0><<<(NSEQ/128)*(HDK/128), 256, 0, stream>>>(xnh, xnl, WkTh, WkTl, kh, kl, nullptr, NSEQ, HDK, DIMX);
  k_gemm<0><<<(NSEQ/128)*(HDV/128), 256, 0, stream>>>(xnh, WvT, (void*)v_rm, nullptr, NSEQ, HDV, DIMX);

  k_abtab<<<dim3(NSEQ, NHEAD), 64, 0, stream>>>(qph, qpl, Wr, cb, pb, ab);
  k_T<<<dim3(HDV/64, NSEQ/64), 256, 0, stream>>>(v_rm, vt, NSEQ, HDV);

  k_attn<<<NSEQ/64*NHEAD, 256, 0, stream>>>(qph, qpl, kh, kl, vt, ab, lut, Obuf);

  k_gemm<1><<<(NSEQ/128)*(DIMX/128), 256, 0, stream>>>(Obuf, WoT, (void*)out, bo, NSEQ, DIMX, HDV);
}

// Round 8
// 608.909 us; speedup vs baseline: 1.5674x; 1.5674x over previous
//
#include <hip/hip_runtime.h>
#include <hip/hip_bf16.h>
#include <math.h>

typedef __hip_bfloat16 bf16;
typedef __attribute__((ext_vector_type(8))) short bf16x8;
typedef __attribute__((ext_vector_type(4))) float f32x4;

#define DIMX 1536
#define NSEQ 4096
#define NHEAD 8
#define DKH 64
#define DVH 192
#define HDK 512
#define HDV 1536
#define KSPLIT 2
#define KVB 32

static __device__ __forceinline__ float b2f(bf16 x){ return __bfloat162float(x); }
static __device__ __forceinline__ bf16 f2b(float x){ return __float2bfloat16(x); }

#define GLD_TO_LDS(gsrc, ldst) __builtin_amdgcn_global_load_lds( \
    (const __attribute__((address_space(1))) unsigned int*)(gsrc), \
    (__attribute__((address_space(3))) unsigned int*)(ldst), 16, 0, 0)

// ---------------- convert fp32 (K,N) -> bf16 (N,K), single ----------------
__global__ __launch_bounds__(256) void k_cvtT(const float* __restrict__ W, bf16* __restrict__ WT, int K, int N){
  __shared__ float t[32][33];
  int n0 = blockIdx.x<<5, k0 = blockIdx.y<<5;
  int tx = threadIdx.x & 31, ty = threadIdx.x >> 5;
  #pragma unroll
  for (int r=ty; r<32; r+=8) t[r][tx] = W[(size_t)(k0+r)*N + n0 + tx];
  __syncthreads();
  #pragma unroll
  for (int r=ty; r<32; r+=8) WT[(size_t)(n0+r)*K + k0 + tx] = f2b(t[tx][r]);
}

// ---------------- convert fp32 (K,N) -> bf16 hi/lo (N,K) ----------------
__global__ __launch_bounds__(256) void k_cvtT2(const float* __restrict__ W, bf16* __restrict__ WTh,
                                               bf16* __restrict__ WTl, int K, int N){
  __shared__ float t[32][33];
  int n0 = blockIdx.x<<5, k0 = blockIdx.y<<5;
  int tx = threadIdx.x & 31, ty = threadIdx.x >> 5;
  #pragma unroll
  for (int r=ty; r<32; r+=8) t[r][tx] = W[(size_t)(k0+r)*N + n0 + tx];
  __syncthreads();
  #pragma unroll
  for (int r=ty; r<32; r+=8){
    float v = t[tx][r];
    bf16 hi = f2b(v);
    WTh[(size_t)(n0+r)*K + k0 + tx] = hi;
    WTl[(size_t)(n0+r)*K + k0 + tx] = f2b(v - b2f(hi));
  }
}

// ---------------- bf16 transpose (R,C)->(C,R), kv-chunk swizzled for attn V staging ----------------
// dst element (dv, kv) stored at kv' = (kv&~31) | (((kv>>3 & 3) ^ (dv&3))<<3) | (kv&7)
__global__ __launch_bounds__(256) void k_T(const bf16* __restrict__ src, bf16* __restrict__ dst, int R, int C){
  __shared__ bf16 t[64][65];
  int c0 = blockIdx.x<<6, r0 = blockIdx.y<<6;
  int tx = threadIdx.x & 63, ty = threadIdx.x >> 6;
  for (int r=ty; r<64; r+=4) t[r][tx] = src[(size_t)(r0+r)*C + c0 + tx];
  __syncthreads();
  for (int r=ty; r<64; r+=4){
    int dv = c0+r, kv = r0+tx;
    int kvp = (kv & ~31) | ((((kv>>3)&3) ^ (dv&3))<<3) | (kv&7);
    dst[(size_t)dv*R + kvp] = t[tx][r];
  }
}

// ---------------- LayerNorm -> bf16 hi/lo ----------------
__global__ __launch_bounds__(256) void k_ln(const float* __restrict__ x, const float* __restrict__ g,
                                            const float* __restrict__ b,
                                            bf16* __restrict__ xnh, bf16* __restrict__ xnl){
  int row = blockIdx.x, t = threadIdx.x;
  const float* xr = x + (size_t)row*DIMX;
  float v[6]; float s=0.f, ss=0.f;
  #pragma unroll
  for (int j=0;j<6;++j){ v[j]=xr[t+256*j]; s+=v[j]; ss+=v[j]*v[j]; }
  int lane = t&63, wave = t>>6;
  #pragma unroll
  for (int off=32; off>0; off>>=1){ s += __shfl_down(s,off,64); ss += __shfl_down(ss,off,64); }
  __shared__ float red[8];
  if (lane==0){ red[wave]=s; red[wave+4]=ss; }
  __syncthreads();
  s = red[0]+red[1]+red[2]+red[3];
  ss = red[4]+red[5]+red[6]+red[7];
  float mu = s*(1.f/DIMX);
  float var = ss*(1.f/DIMX) - mu*mu;
  float rstd = rsqrtf(var + 1e-3f);
  #pragma unroll
  for (int j=0;j<6;++j){
    int c = t+256*j;
    float xv = (v[j]-mu)*rstd*g[c] + b[c];
    bf16 hi = f2b(xv);
    xnh[(size_t)row*DIMX + c] = hi;
    xnl[(size_t)row*DIMX + c] = f2b(xv - b2f(hi));
  }
}

// ---------------- generic bf16 MFMA GEMM ----------------
template<int EPI>
__global__ __launch_bounds__(256) void k_gemm(const bf16* __restrict__ A, const bf16* __restrict__ BT,
    void* __restrict__ Cout, const float* __restrict__ bias, int M, int N, int K)
{
  __shared__ bf16 As[128][32];
  __shared__ bf16 Bs[128][32];
  int nbx = N>>7;
  int m0 = (blockIdx.x / nbx)<<7, n0 = (blockIdx.x % nbx)<<7;
  int tid = threadIdx.x, wave = tid>>6, lane = tid&63;
  int lr = lane&15, lc = lane>>4;
  int wm = (wave>>1)<<6, wn = (wave&1)<<6;
  f32x4 acc[4][4] = {};
  for (int k0=0; k0<K; k0+=32){
    __syncthreads();
    #pragma unroll
    for (int it=0; it<2; ++it){
      int id = tid + (it<<8);
      int rr = id>>2, cc = id&3;
      unsigned wbase = (unsigned)(((it<<8) + (tid & 192))*16);
      GLD_TO_LDS(A  + (size_t)(m0+rr)*K + k0 + cc*8, (char*)As + wbase);
      GLD_TO_LDS(BT + (size_t)(n0+rr)*K + k0 + cc*8, (char*)Bs + wbase);
    }
    __syncthreads();
    bf16x8 af[4], bfr[4];
    #pragma unroll
    for (int mt=0; mt<4; ++mt) af[mt] = *(const bf16x8*)(&As[wm + mt*16 + lr][lc*8]);
    #pragma unroll
    for (int nt=0; nt<4; ++nt) bfr[nt] = *(const bf16x8*)(&Bs[wn + nt*16 + lr][lc*8]);
    #pragma unroll
    for (int mt=0; mt<4; ++mt)
      #pragma unroll
      for (int nt=0; nt<4; ++nt)
        acc[mt][nt] = __builtin_amdgcn_mfma_f32_16x16x32_bf16(af[mt], bfr[nt], acc[mt][nt], 0,0,0);
  }
  #pragma unroll
  for (int mt=0; mt<4; ++mt){
    #pragma unroll
    for (int nt=0; nt<4; ++nt){
      #pragma unroll
      for (int reg=0; reg<4; ++reg){
        int row = m0 + wm + mt*16 + (lc<<2) + reg;
        int col = n0 + wn + nt*16 + lr;
        if (EPI==0) ((bf16*)Cout)[(size_t)row*N + col] = f2b(acc[mt][nt][reg]);
        else        ((float*)Cout)[(size_t)row*N + col] = acc[mt][nt][reg] + bias[col];
      }
    }
  }
}

// ---------------- split (compensated) GEMM: fp32-accurate C = A @ BT^T ----------------
// EPIQ 0 (K path): store hi/lo with d-chunk swizzle (col' = chunk^(row&7)) for attn LDS staging.
// EPIQ 1 (Q path): store hi/lo of (acc*0.125 + cb[col]), unswizzled.
template<int EPIQ>
__global__ __launch_bounds__(256) void k_gemm3(const bf16* __restrict__ Ahi, const bf16* __restrict__ Alo,
    const bf16* __restrict__ Bhi, const bf16* __restrict__ Blo,
    bf16* __restrict__ Ohi, bf16* __restrict__ Olo,
    const float* __restrict__ cb, int M, int N, int K)
{
  __shared__ bf16 Ash[128][32];
  __shared__ bf16 Asl[128][32];
  __shared__ bf16 Bsh[128][32];
  __shared__ bf16 Bsl[128][32];
  int nbx = N>>7;
  int m0 = (blockIdx.x / nbx)<<7, n0 = (blockIdx.x % nbx)<<7;
  int tid = threadIdx.x, wave = tid>>6, lane = tid&63;
  int lr = lane&15, lc = lane>>4;
  int wm = (wave>>1)<<6, wn = (wave&1)<<6;
  f32x4 acc[4][4] = {};
  for (int k0=0; k0<K; k0+=32){
    __syncthreads();
    #pragma unroll
    for (int it=0; it<2; ++it){
      int id = tid + (it<<8);
      int rr = id>>2, cc = id&3;
      unsigned wbase = (unsigned)(((it<<8) + (tid & 192))*16);
      size_t ga = (size_t)(m0+rr)*K + k0 + cc*8;
      size_t gb = (size_t)(n0+rr)*K + k0 + cc*8;
      GLD_TO_LDS(Ahi + ga, (char*)Ash + wbase);
      GLD_TO_LDS(Alo + ga, (char*)Asl + wbase);
      GLD_TO_LDS(Bhi + gb, (char*)Bsh + wbase);
      GLD_TO_LDS(Blo + gb, (char*)Bsl + wbase);
    }
    __syncthreads();
    bf16x8 ah[4], al[4], bh[4], bl[4];
    #pragma unroll
    for (int mt=0; mt<4; ++mt){
      ah[mt] = *(const bf16x8*)(&Ash[wm + mt*16 + lr][lc*8]);
      al[mt] = *(const bf16x8*)(&Asl[wm + mt*16 + lr][lc*8]);
    }
    #pragma unroll
    for (int nt=0; nt<4; ++nt){
      bh[nt] = *(const bf16x8*)(&Bsh[wn + nt*16 + lr][lc*8]);
      bl[nt] = *(const bf16x8*)(&Bsl[wn + nt*16 + lr][lc*8]);
    }
    #pragma unroll
    for (int mt=0; mt<4; ++mt)
      #pragma unroll
      for (int nt=0; nt<4; ++nt){
        acc[mt][nt] = __builtin_amdgcn_mfma_f32_16x16x32_bf16(ah[mt], bh[nt], acc[mt][nt], 0,0,0);
        acc[mt][nt] = __builtin_amdgcn_mfma_f32_16x16x32_bf16(al[mt], bh[nt], acc[mt][nt], 0,0,0);
        acc[mt][nt] = __builtin_amdgcn_mfma_f32_16x16x32_bf16(ah[mt], bl[nt], acc[mt][nt], 0,0,0);
      }
  }
  #pragma unroll
  for (int mt=0; mt<4; ++mt){
    #pragma unroll
    for (int nt=0; nt<4; ++nt){
      #pragma unroll
      for (int reg=0; reg<4; ++reg){
        int row = m0 + wm + mt*16 + (lc<<2) + reg;
        int col = n0 + wn + nt*16 + lr;
        float v = acc[mt][nt][reg];
        int colw = col;
        if (EPIQ==1) v = v*0.125f + cb[col & (HDK-1)];
        else colw = (col & ~63) | ((((col>>3)&7) ^ (row&7))<<3) | (col&7);
        bf16 hi = f2b(v);
        Ohi[(size_t)row*N + colw] = hi;
        Olo[(size_t)row*N + colw] = f2b(v - b2f(hi));
      }
    }
  }
}

// ---------------- per (h,i): u = Wr_h^T (qp - cb + pb), suffix sums A/B ----------------
__global__ __launch_bounds__(64) void k_abtab(const bf16* __restrict__ qph, const bf16* __restrict__ qpl,
                                              const float* __restrict__ Wr,
                                              const float* __restrict__ cb, const float* __restrict__ pb,
                                              float* __restrict__ ab){
  int i = blockIdx.x, h = blockIdx.y;
  int lane = threadIdx.x;
  __shared__ float qpp[64];
  __shared__ float us[32];
  size_t qi = (size_t)i*HDK + h*DKH + lane;
  int col = h*DKH + lane;
  qpp[lane] = b2f(qph[qi]) + b2f(qpl[qi]) - cb[col] + pb[col];
  __syncthreads();
  if (lane < 32){
    const float* wr = Wr + (size_t)lane*HDK + h*DKH;
    float u=0.f;
    #pragma unroll
    for (int d2=0; d2<64; ++d2) u += wr[d2]*qpp[d2];
    us[lane]=u;
  }
  __syncthreads();
  if (lane < 16){
    float a=0.f, bb=0.f;
    for (int f=15; f>=lane; --f){ a += us[f]; bb += us[16+f]; }
    float* o = ab + ((size_t)h*NSEQ + i)*32;
    o[lane]=a; o[16+lane]=bb;
  }
}

// ---------------- flash attention, KV-split, LDS-staged (gld_lds + pre-swizzled K/V) ----------------
__global__ __launch_bounds__(256,4) void k_attn(
    const bf16* __restrict__ qph, const bf16* __restrict__ qpl,
    const bf16* __restrict__ khs, const bf16* __restrict__ kls,
    const bf16* __restrict__ vts, const float* __restrict__ ab,
    bf16* __restrict__ PO, float2* __restrict__ ML)
{
  int wg = blockIdx.x;
  int h  = wg & 7;
  int qtile = (wg >> 3) & 63;
  int ks = wg >> 9;
  int q0 = qtile * 64;
  int tid = threadIdx.x, wave = tid>>6, lane = tid&63;
  int lr = lane&15, lc = lane>>4;

  __shared__ bf16 Ksh[KVB][64];    // chunk^(row&7) swizzle (pre-swizzled in global)
  __shared__ bf16 Ksl[KVB][64];
  __shared__ bf16 Vs[DVH][KVB];    // chunk^(dv&3) swizzle (pre-swizzled in global)
  __shared__ bf16 Ps[4][16][40];   // per-wave P, row pad 40
  __shared__ float2 ABs[64][17];   // (sym,asy) suffix tables

  for (int xx=tid; xx<1024; xx+=256){
    int row = xx>>4, g = xx&15;
    const float* src = ab + ((size_t)h*NSEQ + q0 + row)*32;
    ABs[row][g] = make_float2(src[g], src[16+g]);
  }

  bf16x8 qfh[2], qfl[2];
  {
    int row = q0 + wave*16 + lr;
    const bf16* qrh = qph + (size_t)row*HDK + h*DKH;
    const bf16* qrl = qpl + (size_t)row*HDK + h*DKH;
    qfh[0] = *(const bf16x8*)(qrh + 8*lc);
    qfh[1] = *(const bf16x8*)(qrh + 32 + 8*lc);
    qfl[0] = *(const bf16x8*)(qrl + 8*lc);
    qfl[1] = *(const bf16x8*)(qrl + 32 + 8*lc);
  }
  const bf16* Kh = khs + h*DKH;
  const bf16* Kl = kls + h*DKH;
  const bf16* Vt = vts + (size_t)h*DVH*NSEQ;

  f32x4 oacc[12] = {};
  float mrow[4], lrow[4];
  #pragma unroll
  for (int r=0;r<4;++r){ mrow[r]=-3e38f; lrow[r]=0.f; }

  const float RCPL = 1.33329424f;  // 16 / log2(4097)
  int kv_lo = ks * (NSEQ/KSPLIT);
  int kv_hi = kv_lo + NSEQ/KSPLIT;

  for (int kv0=kv_lo; kv0<kv_hi; kv0+=KVB) {
    __syncthreads();
    { // stage K (32x64 hi+lo) and V (192x32), all linear-dest DMA
      int r = tid>>3, c = tid&7;
      size_t gk = (size_t)(kv0+r)*HDK + c*8;
      GLD_TO_LDS(Kh + gk, (char*)Ksh + (tid&192)*16);
      GLD_TO_LDS(Kl + gk, (char*)Ksl + (tid&192)*16);
      #pragma unroll
      for (int j=0; j<3; ++j){
        int id = j*256 + tid;
        int vr = id>>2, vc = id&3;
        GLD_TO_LDS(Vt + (size_t)vr*NSEQ + kv0 + vc*8, (char*)Vs + (j*256 + (tid&192))*16);
      }
    }
    __syncthreads();

    // S = Q K^T (16 q-rows/wave x 32 keys), compensated
    f32x4 sf[2];
    #pragma unroll
    for (int ct=0; ct<2; ++ct){
      f32x4 s = {};
      int krow = ct*16 + lr;
      int sw0 = ((lc  ) ^ (krow&7))*8;
      int sw1 = ((lc+4) ^ (krow&7))*8;
      bf16x8 kh0 = *(const bf16x8*)(&Ksh[krow][sw0]);
      bf16x8 kh1 = *(const bf16x8*)(&Ksh[krow][sw1]);
      bf16x8 kl0 = *(const bf16x8*)(&Ksl[krow][sw0]);
      bf16x8 kl1 = *(const bf16x8*)(&Ksl[krow][sw1]);
      s = __builtin_amdgcn_mfma_f32_16x16x32_bf16(qfh[0], kh0, s, 0,0,0);
      s = __builtin_amdgcn_mfma_f32_16x16x32_bf16(qfh[1], kh1, s, 0,0,0);
      s = __builtin_amdgcn_mfma_f32_16x16x32_bf16(qfl[0], kh0, s, 0,0,0);
      s = __builtin_amdgcn_mfma_f32_16x16x32_bf16(qfl[1], kh1, s, 0,0,0);
      s = __builtin_amdgcn_mfma_f32_16x16x32_bf16(qfh[0], kl0, s, 0,0,0);
      s = __builtin_amdgcn_mfma_f32_16x16x32_bf16(qfh[1], kl1, s, 0,0,0);
      sf[ct]=s;
    }
    // decomposed rel-pos bias: g = floor(16*log2(ad)/log2(4097)); ad=0 -> g=0.
    // NOTE: guard must be a select, NOT (ad|1) — that corrupts every even ad (R7 bug).
    float mnew[4];
    #pragma unroll
    for (int r=0;r<4;++r) mnew[r]=mrow[r];
    #pragma unroll
    for (int ct=0; ct<2; ++ct){
      int j = kv0 + ct*16 + lr;
      #pragma unroll
      for (int reg=0; reg<4; ++reg){
        int rowloc = wave*16 + 4*lc + reg;
        int dd = j - (q0 + rowloc);
        int ad = dd<0 ? -dd : dd;
        int gg = ad ? (int)(__log2f((float)ad) * RCPL) : 0;
        float2 sb = ABs[rowloc][gg];
        float bias = sb.x + (dd>0 ? sb.y : (dd<0 ? -sb.y : 0.f));
        float sv = sf[ct][reg] + bias;
        sf[ct][reg] = sv;
        mnew[reg] = fmaxf(mnew[reg], sv);
      }
    }
    #pragma unroll
    for (int off=1; off<16; off<<=1){
      #pragma unroll
      for (int r=0;r<4;++r) mnew[r] = fmaxf(mnew[r], __shfl_xor(mnew[r], off, 64));
    }
    float scl[4];
    #pragma unroll
    for (int r=0;r<4;++r){
      scl[r] = __expf(mrow[r]-mnew[r]);
      mrow[r]=mnew[r];
      lrow[r]*=scl[r];
    }
    #pragma unroll
    for (int ct=0; ct<2; ++ct){
      #pragma unroll
      for (int reg=0; reg<4; ++reg){
        float p = __expf(sf[ct][reg]-mrow[reg]);
        lrow[reg]+=p;
        Ps[wave][4*lc+reg][ct*16+lr] = f2b(p);
      }
    }
    #pragma unroll
    for (int t12=0;t12<12;++t12){
      #pragma unroll
      for (int reg=0;reg<4;++reg) oacc[t12][reg]*=scl[reg];
    }
    bf16x8 pa = *(const bf16x8*)(&Ps[wave][lr][lc*8]);
    #pragma unroll
    for (int t12=0; t12<12; ++t12){
      int vrow = t12*16 + lr;
      bf16x8 v0 = *(const bf16x8*)(&Vs[vrow][(lc ^ (vrow&3))*8]);
      oacc[t12] = __builtin_amdgcn_mfma_f32_16x16x32_bf16(pa, v0, oacc[t12], 0,0,0);
    }
  }
  // emit partials (unnormalized O + m,l)
  #pragma unroll
  for (int off=1; off<16; off<<=1){
    #pragma unroll
    for (int r=0;r<4;++r) lrow[r] += __shfl_xor(lrow[r], off, 64);
  }
  #pragma unroll
  for (int t12=0;t12<12;++t12){
    #pragma unroll
    for (int reg=0;reg<4;++reg){
      int rowloc = wave*16 + 4*lc + reg;
      PO[((size_t)wg*64 + rowloc)*DVH + t12*16 + lr] = f2b(oacc[t12][reg]);
    }
  }
  if (lr == 0){
    #pragma unroll
    for (int reg=0; reg<4; ++reg){
      int rowloc = wave*16 + 4*lc + reg;
      ML[(size_t)wg*64 + rowloc] = make_float2(mrow[reg], lrow[reg]);
    }
  }
}

// ---------------- combine KV-split partials -> Obuf bf16 [NSEQ][HDV] ----------------
__global__ __launch_bounds__(256) void k_comb(const bf16* __restrict__ PO, const float2* __restrict__ ML,
                                              bf16* __restrict__ Obuf){
  int i = blockIdx.x;
  int qtile = i>>6, rl = i&63;
  for (int c=threadIdx.x; c<HDV; c+=256){
    int h = c/DVH, d = c - h*DVH;
    int wg0 = qtile*8 + h, wg1 = 512 + wg0;
    float2 ml0 = ML[(size_t)wg0*64 + rl];
    float2 ml1 = ML[(size_t)wg1*64 + rl];
    float M = fmaxf(ml0.x, ml1.x);
    float w0 = __expf(ml0.x - M), w1 = __expf(ml1.x - M);
    float l = ml0.y*w0 + ml1.y*w1;
    float o = b2f(PO[((size_t)wg0*64 + rl)*DVH + d])*w0
            + b2f(PO[((size_t)wg1*64 + rl)*DVH + d])*w1;
    Obuf[(size_t)i*HDV + c] = f2b(o / l);
  }
}

extern "C" void kernel_launch(void* const* d_in, const int* in_sizes, int n_in,
                              void* d_out, int out_size, void* d_ws, size_t ws_size,
                              hipStream_t stream) {
  const float* x  = (const float*)d_in[0];
  const float* lg = (const float*)d_in[1];
  const float* lb = (const float*)d_in[2];
  const float* Wq = (const float*)d_in[3];
  const float* Wk = (const float*)d_in[4];
  const float* Wv = (const float*)d_in[5];
  const float* Wr = (const float*)d_in[6];
  const float* Wo = (const float*)d_in[7];
  const float* bo = (const float*)d_in[8];
  const float* cb = (const float*)d_in[9];
  const float* pb = (const float*)d_in[10];
  float* out = (float*)d_out;

  char* ws = (char*)d_ws;
  size_t off = 0;
  auto alloc = [&](size_t bytes)->void*{ void* p = ws + off; off += (bytes + 255) & ~(size_t)255; return p; };
  // persistent through k_attn:
  bf16* WoT  = (bf16*)alloc((size_t)DIMX*HDV*2);
  bf16* qph  = (bf16*)alloc((size_t)NSEQ*HDK*2);
  bf16* qpl  = (bf16*)alloc((size_t)NSEQ*HDK*2);
  bf16* kh   = (bf16*)alloc((size_t)NSEQ*HDK*2);   // d-chunk swizzled
  bf16* kl   = (bf16*)alloc((size_t)NSEQ*HDK*2);   // d-chunk swizzled
  bf16* vt   = (bf16*)alloc((size_t)HDV*NSEQ*2);   // kv-chunk swizzled
  float* ab  = (float*)alloc((size_t)NHEAD*NSEQ*32*4);
  bf16* Obuf = (bf16*)alloc((size_t)NSEQ*HDV*2);
  float2* ML = (float2*)alloc((size_t)KSPLIT*512*64*sizeof(float2));
  // scratch (dead before k_attn) — PO aliases it:
  char* scratch = (char*)alloc(0);
  bf16* xnh  = (bf16*)alloc((size_t)NSEQ*DIMX*2);
  bf16* xnl  = (bf16*)alloc((size_t)NSEQ*DIMX*2);
  bf16* v_rm = (bf16*)alloc((size_t)NSEQ*HDV*2);
  bf16* WqTh = (bf16*)alloc((size_t)HDK*DIMX*2);
  bf16* WqTl = (bf16*)alloc((size_t)HDK*DIMX*2);
  bf16* WkTh = (bf16*)alloc((size_t)HDK*DIMX*2);
  bf16* WkTl = (bf16*)alloc((size_t)HDK*DIMX*2);
  bf16* WvT  = (bf16*)alloc((size_t)HDV*DIMX*2);
  bf16* PO   = (bf16*)scratch;   // KSPLIT*512*64*192*2 = 24 MB <= xnh+xnl
  (void)in_sizes; (void)n_in; (void)out_size; (void)ws_size;

  k_cvtT2<<<dim3(HDK/32,  DIMX/32), 256, 0, stream>>>(Wq, WqTh, WqTl, DIMX, HDK);
  k_cvtT2<<<dim3(HDK/32,  DIMX/32), 256, 0, stream>>>(Wk, WkTh, WkTl, DIMX, HDK);
  k_cvtT <<<dim3(HDV/32,  DIMX/32), 256, 0, stream>>>(Wv, WvT, DIMX, HDV);
  k_cvtT <<<dim3(DIMX/32, HDV/32),  256, 0, stream>>>(Wo, WoT, HDV, DIMX);
  k_ln<<<NSEQ, 256, 0, stream>>>(x, lg, lb, xnh, xnl);

  k_gemm3<1><<<(NSEQ/128)*(HDK/128), 256, 0, stream>>>(xnh, xnl, WqTh, WqTl, qph, qpl, cb, NSEQ, HDK, DIMX);
  k_gemm3<0><<<(NSEQ/128)*(HDK/128), 256, 0, stream>>>(xnh, xnl, WkTh, WkTl, kh, kl, nullptr, NSEQ, HDK, DIMX);
  k_gemm<0><<<(NSEQ/128)*(HDV/128), 256, 0, stream>>>(xnh, WvT, (void*)v_rm, nullptr, NSEQ, HDV, DIMX);

  k_abtab<<<dim3(NSEQ, NHEAD), 64, 0, stream>>>(qph, qpl, Wr, cb, pb, ab);
  k_T<<<dim3(HDV/64, NSEQ/64), 256, 0, stream>>>(v_rm, vt, NSEQ, HDV);

  k_attn<<<KSPLIT*512, 256, 0, stream>>>(qph, qpl, kh, kl, vt, ab, PO, ML);
  k_comb<<<NSEQ, 256, 0, stream>>>(PO, ML, Obuf);

  k_gemm<1><<<(NSEQ/128)*(DIMX/128), 256, 0, stream>>>(Obuf, WoT, (void*)out, bo, NSEQ, DIMX, HDV);
}

// Round 9
// 564.444 us; speedup vs baseline: 1.6909x; 1.0788x over previous
//
#include <hip/hip_runtime.h>
#include <hip/hip_bf16.h>
#include <math.h>

typedef __hip_bfloat16 bf16;
typedef __attribute__((ext_vector_type(8))) short bf16x8;
typedef __attribute__((ext_vector_type(4))) float f32x4;

#define DIMX 1536
#define NSEQ 4096
#define NHEAD 8
#define DKH 64
#define DVH 192
#define HDK 512
#define HDV 1536
#define KSPLIT 2
#define KVB 32

static __device__ __forceinline__ float b2f(bf16 x){ return __bfloat162float(x); }
static __device__ __forceinline__ bf16 f2b(float x){ return __float2bfloat16(x); }

#define GLD_TO_LDS(gsrc, ldst) __builtin_amdgcn_global_load_lds( \
    (const __attribute__((address_space(1))) unsigned int*)(gsrc), \
    (__attribute__((address_space(3))) unsigned int*)(ldst), 16, 0, 0)

// XCD-aware chunked remap (valid when gridDim.x % 8 == 0): consecutive tiles share an XCD L2.
static __device__ __forceinline__ int xcd_swz(int b, int nwg){
  return (b & 7)*(nwg>>3) + (b>>3);
}

// ---------------- convert fp32 (K,N) -> bf16 (N,K) ----------------
__global__ __launch_bounds__(256) void k_cvtT(const float* __restrict__ W, bf16* __restrict__ WT, int K, int N){
  __shared__ float t[32][33];
  int n0 = blockIdx.x<<5, k0 = blockIdx.y<<5;
  int tx = threadIdx.x & 31, ty = threadIdx.x >> 5;
  #pragma unroll
  for (int r=ty; r<32; r+=8) t[r][tx] = W[(size_t)(k0+r)*N + n0 + tx];
  __syncthreads();
  #pragma unroll
  for (int r=ty; r<32; r+=8) WT[(size_t)(n0+r)*K + k0 + tx] = f2b(t[tx][r]);
}

// ---------------- bf16 transpose (R,C)->(C,R), kv-chunk swizzled for attn V staging ----------------
// dst element (dv, kv) stored at kv' = (kv&~31) | (((kv>>3 & 3) ^ ((dv>>1)&3))<<3) | (kv&7)
// NOTE (dv>>1)&3, not (dv&3): Vs row stride is 64B (16 words), so rows alias banks every 2 rows;
// the swizzle must mix dv bits 1..2, not bit 0, to spread the PV read across banks (R8: 4-way -> 2-way).
__global__ __launch_bounds__(256) void k_T(const bf16* __restrict__ src, bf16* __restrict__ dst, int R, int C){
  __shared__ bf16 t[64][65];
  int c0 = blockIdx.x<<6, r0 = blockIdx.y<<6;
  int tx = threadIdx.x & 63, ty = threadIdx.x >> 6;
  for (int r=ty; r<64; r+=4) t[r][tx] = src[(size_t)(r0+r)*C + c0 + tx];
  __syncthreads();
  for (int r=ty; r<64; r+=4){
    int dv = c0+r, kv = r0+tx;
    int kvp = (kv & ~31) | ((((kv>>3)&3) ^ ((dv>>1)&3))<<3) | (kv&7);
    dst[(size_t)dv*R + kvp] = t[tx][r];
  }
}

// ---------------- LayerNorm -> bf16 hi/lo ----------------
__global__ __launch_bounds__(256) void k_ln(const float* __restrict__ x, const float* __restrict__ g,
                                            const float* __restrict__ b,
                                            bf16* __restrict__ xnh, bf16* __restrict__ xnl){
  int row = blockIdx.x, t = threadIdx.x;
  const float* xr = x + (size_t)row*DIMX;
  float v[6]; float s=0.f, ss=0.f;
  #pragma unroll
  for (int j=0;j<6;++j){ v[j]=xr[t+256*j]; s+=v[j]; ss+=v[j]*v[j]; }
  int lane = t&63, wave = t>>6;
  #pragma unroll
  for (int off=32; off>0; off>>=1){ s += __shfl_down(s,off,64); ss += __shfl_down(ss,off,64); }
  __shared__ float red[8];
  if (lane==0){ red[wave]=s; red[wave+4]=ss; }
  __syncthreads();
  s = red[0]+red[1]+red[2]+red[3];
  ss = red[4]+red[5]+red[6]+red[7];
  float mu = s*(1.f/DIMX);
  float var = ss*(1.f/DIMX) - mu*mu;
  float rstd = rsqrtf(var + 1e-3f);
  #pragma unroll
  for (int j=0;j<6;++j){
    int c = t+256*j;
    float xv = (v[j]-mu)*rstd*g[c] + b[c];
    bf16 hi = f2b(xv);
    xnh[(size_t)row*DIMX + c] = hi;
    xnl[(size_t)row*DIMX + c] = f2b(xv - b2f(hi));
  }
}

// ---------------- generic bf16 MFMA GEMM ----------------
template<int EPI>
__global__ __launch_bounds__(256) void k_gemm(const bf16* __restrict__ A, const bf16* __restrict__ BT,
    void* __restrict__ Cout, const float* __restrict__ bias, int M, int N, int K)
{
  __shared__ bf16 As[128][32];
  __shared__ bf16 Bs[128][32];
  int nbx = N>>7;
  int bid = xcd_swz(blockIdx.x, gridDim.x);
  int m0 = (bid / nbx)<<7, n0 = (bid % nbx)<<7;
  int tid = threadIdx.x, wave = tid>>6, lane = tid&63;
  int lr = lane&15, lc = lane>>4;
  int wm = (wave>>1)<<6, wn = (wave&1)<<6;
  f32x4 acc[4][4] = {};
  for (int k0=0; k0<K; k0+=32){
    __syncthreads();
    #pragma unroll
    for (int it=0; it<2; ++it){
      int id = tid + (it<<8);
      int rr = id>>2, cc = id&3;
      unsigned wbase = (unsigned)(((it<<8) + (tid & 192))*16);
      GLD_TO_LDS(A  + (size_t)(m0+rr)*K + k0 + cc*8, (char*)As + wbase);
      GLD_TO_LDS(BT + (size_t)(n0+rr)*K + k0 + cc*8, (char*)Bs + wbase);
    }
    __syncthreads();
    bf16x8 af[4], bfr[4];
    #pragma unroll
    for (int mt=0; mt<4; ++mt) af[mt] = *(const bf16x8*)(&As[wm + mt*16 + lr][lc*8]);
    #pragma unroll
    for (int nt=0; nt<4; ++nt) bfr[nt] = *(const bf16x8*)(&Bs[wn + nt*16 + lr][lc*8]);
    #pragma unroll
    for (int mt=0; mt<4; ++mt)
      #pragma unroll
      for (int nt=0; nt<4; ++nt)
        acc[mt][nt] = __builtin_amdgcn_mfma_f32_16x16x32_bf16(af[mt], bfr[nt], acc[mt][nt], 0,0,0);
  }
  #pragma unroll
  for (int mt=0; mt<4; ++mt){
    #pragma unroll
    for (int nt=0; nt<4; ++nt){
      #pragma unroll
      for (int reg=0; reg<4; ++reg){
        int row = m0 + wm + mt*16 + (lc<<2) + reg;
        int col = n0 + wn + nt*16 + lr;
        if (EPI==0) ((bf16*)Cout)[(size_t)row*N + col] = f2b(acc[mt][nt][reg]);
        else        ((float*)Cout)[(size_t)row*N + col] = acc[mt][nt][reg] + bias[col];
      }
    }
  }
}

// ---------------- split (compensated) GEMM: C = (Ahi+Alo) @ Bhi^T ----------------
// W-lo term dropped (delta-S ~1e-3, far under budget). B single bf16.
// EPIQ 0 (K path): store hi/lo with d-chunk swizzle for attn staging.
// EPIQ 1 (Q path): store hi/lo of (acc*0.125 + cb[col]).
template<int EPIQ>
__global__ __launch_bounds__(256) void k_gemm3(const bf16* __restrict__ Ahi, const bf16* __restrict__ Alo,
    const bf16* __restrict__ Bhi,
    bf16* __restrict__ Ohi, bf16* __restrict__ Olo,
    const float* __restrict__ cb, int M, int N, int K)
{
  __shared__ bf16 Ash[128][32];
  __shared__ bf16 Asl[128][32];
  __shared__ bf16 Bsh[128][32];
  int nbx = N>>7;
  int bid = xcd_swz(blockIdx.x, gridDim.x);
  int m0 = (bid / nbx)<<7, n0 = (bid % nbx)<<7;
  int tid = threadIdx.x, wave = tid>>6, lane = tid&63;
  int lr = lane&15, lc = lane>>4;
  int wm = (wave>>1)<<6, wn = (wave&1)<<6;
  f32x4 acc[4][4] = {};
  for (int k0=0; k0<K; k0+=32){
    __syncthreads();
    #pragma unroll
    for (int it=0; it<2; ++it){
      int id = tid + (it<<8);
      int rr = id>>2, cc = id&3;
      unsigned wbase = (unsigned)(((it<<8) + (tid & 192))*16);
      size_t ga = (size_t)(m0+rr)*K + k0 + cc*8;
      size_t gb = (size_t)(n0+rr)*K + k0 + cc*8;
      GLD_TO_LDS(Ahi + ga, (char*)Ash + wbase);
      GLD_TO_LDS(Alo + ga, (char*)Asl + wbase);
      GLD_TO_LDS(Bhi + gb, (char*)Bsh + wbase);
    }
    __syncthreads();
    bf16x8 ah[4], al[4], bh[4];
    #pragma unroll
    for (int mt=0; mt<4; ++mt){
      ah[mt] = *(const bf16x8*)(&Ash[wm + mt*16 + lr][lc*8]);
      al[mt] = *(const bf16x8*)(&Asl[wm + mt*16 + lr][lc*8]);
    }
    #pragma unroll
    for (int nt=0; nt<4; ++nt)
      bh[nt] = *(const bf16x8*)(&Bsh[wn + nt*16 + lr][lc*8]);
    #pragma unroll
    for (int mt=0; mt<4; ++mt)
      #pragma unroll
      for (int nt=0; nt<4; ++nt){
        acc[mt][nt] = __builtin_amdgcn_mfma_f32_16x16x32_bf16(ah[mt], bh[nt], acc[mt][nt], 0,0,0);
        acc[mt][nt] = __builtin_amdgcn_mfma_f32_16x16x32_bf16(al[mt], bh[nt], acc[mt][nt], 0,0,0);
      }
  }
  #pragma unroll
  for (int mt=0; mt<4; ++mt){
    #pragma unroll
    for (int nt=0; nt<4; ++nt){
      #pragma unroll
      for (int reg=0; reg<4; ++reg){
        int row = m0 + wm + mt*16 + (lc<<2) + reg;
        int col = n0 + wn + nt*16 + lr;
        float v = acc[mt][nt][reg];
        int colw = col;
        if (EPIQ==1) v = v*0.125f + cb[col & (HDK-1)];
        else colw = (col & ~63) | ((((col>>3)&7) ^ (row&7))<<3) | (col&7);
        bf16 hi = f2b(v);
        Ohi[(size_t)row*N + colw] = hi;
        Olo[(size_t)row*N + colw] = f2b(v - b2f(hi));
      }
    }
  }
}

// ---------------- per (h,i): u = Wr_h^T (qp - cb + pb), suffix sums A/B ----------------
__global__ __launch_bounds__(64) void k_abtab(const bf16* __restrict__ qph, const bf16* __restrict__ qpl,
                                              const float* __restrict__ Wr,
                                              const float* __restrict__ cb, const float* __restrict__ pb,
                                              float* __restrict__ ab){
  int i = blockIdx.x, h = blockIdx.y;
  int lane = threadIdx.x;
  __shared__ float qpp[64];
  __shared__ float us[32];
  size_t qi = (size_t)i*HDK + h*DKH + lane;
  int col = h*DKH + lane;
  qpp[lane] = b2f(qph[qi]) + b2f(qpl[qi]) - cb[col] + pb[col];
  __syncthreads();
  if (lane < 32){
    const float* wr = Wr + (size_t)lane*HDK + h*DKH;
    float u=0.f;
    #pragma unroll
    for (int d2=0; d2<64; ++d2) u += wr[d2]*qpp[d2];
    us[lane]=u;
  }
  __syncthreads();
  if (lane < 16){
    float a=0.f, bb=0.f;
    for (int f=15; f>=lane; --f){ a += us[f]; bb += us[16+f]; }
    float* o = ab + ((size_t)h*NSEQ + i)*32;
    o[lane]=a; o[16+lane]=bb;
  }
}

// ---------------- flash attention, KV-split, LDS-staged, defer-max ----------------
__global__ __launch_bounds__(256,4) void k_attn(
    const bf16* __restrict__ qph, const bf16* __restrict__ qpl,
    const bf16* __restrict__ khs, const bf16* __restrict__ kls,
    const bf16* __restrict__ vts, const float* __restrict__ ab,
    bf16* __restrict__ PO, float2* __restrict__ ML)
{
  int wg = blockIdx.x;
  int h  = wg & 7;
  int qtile = (wg >> 3) & 63;
  int ks = wg >> 9;
  int q0 = qtile * 64;
  int tid = threadIdx.x, wave = tid>>6, lane = tid&63;
  int lr = lane&15, lc = lane>>4;

  __shared__ bf16 Ksh[KVB][64];    // chunk^(row&7) swizzle (pre-swizzled in global)
  __shared__ bf16 Ksl[KVB][64];
  __shared__ bf16 Vs[DVH][KVB];    // chunk^((dv>>1)&3) swizzle (pre-swizzled in global)
  __shared__ bf16 Ps[4][16][36];   // per-wave P; pad 36 -> conflict-free writes, ~2-way reads
  __shared__ float2 ABs[64][17];   // (sym,asy) suffix tables

  for (int xx=tid; xx<1024; xx+=256){
    int row = xx>>4, g = xx&15;
    const float* src = ab + ((size_t)h*NSEQ + q0 + row)*32;
    ABs[row][g] = make_float2(src[g], src[16+g]);
  }

  bf16x8 qfh[2], qfl[2];
  {
    int row = q0 + wave*16 + lr;
    const bf16* qrh = qph + (size_t)row*HDK + h*DKH;
    const bf16* qrl = qpl + (size_t)row*HDK + h*DKH;
    qfh[0] = *(const bf16x8*)(qrh + 8*lc);
    qfh[1] = *(const bf16x8*)(qrh + 32 + 8*lc);
    qfl[0] = *(const bf16x8*)(qrl + 8*lc);
    qfl[1] = *(const bf16x8*)(qrl + 32 + 8*lc);
  }
  const bf16* Kh = khs + h*DKH;
  const bf16* Kl = kls + h*DKH;
  const bf16* Vt = vts + (size_t)h*DVH*NSEQ;

  f32x4 oacc[12] = {};
  float mrow[4], lrow[4];
  #pragma unroll
  for (int r=0;r<4;++r){ mrow[r]=-3e38f; lrow[r]=0.f; }

  const float RCPL = 1.33329424f;  // 16 / log2(4097)
  int kv_lo = ks * (NSEQ/KSPLIT);
  int kv_hi = kv_lo + NSEQ/KSPLIT;

  for (int kv0=kv_lo; kv0<kv_hi; kv0+=KVB) {
    __syncthreads();
    { // stage K (32x64 hi+lo) and V (192x32), linear-dest DMA
      int r = tid>>3, c = tid&7;
      size_t gk = (size_t)(kv0+r)*HDK + c*8;
      GLD_TO_LDS(Kh + gk, (char*)Ksh + (tid&192)*16);
      GLD_TO_LDS(Kl + gk, (char*)Ksl + (tid&192)*16);
      #pragma unroll
      for (int j=0; j<3; ++j){
        int id = j*256 + tid;
        int vr = id>>2, vc = id&3;
        GLD_TO_LDS(Vt + (size_t)vr*NSEQ + kv0 + vc*8, (char*)Vs + (j*256 + (tid&192))*16);
      }
    }
    __syncthreads();

    // S = Q K^T (16 q-rows/wave x 32 keys), compensated
    f32x4 sf[2];
    #pragma unroll
    for (int ct=0; ct<2; ++ct){
      f32x4 s = {};
      int krow = ct*16 + lr;
      int sw0 = ((lc  ) ^ (krow&7))*8;
      int sw1 = ((lc+4) ^ (krow&7))*8;
      bf16x8 kh0 = *(const bf16x8*)(&Ksh[krow][sw0]);
      bf16x8 kh1 = *(const bf16x8*)(&Ksh[krow][sw1]);
      bf16x8 kl0 = *(const bf16x8*)(&Ksl[krow][sw0]);
      bf16x8 kl1 = *(const bf16x8*)(&Ksl[krow][sw1]);
      s = __builtin_amdgcn_mfma_f32_16x16x32_bf16(qfh[0], kh0, s, 0,0,0);
      s = __builtin_amdgcn_mfma_f32_16x16x32_bf16(qfh[1], kh1, s, 0,0,0);
      s = __builtin_amdgcn_mfma_f32_16x16x32_bf16(qfl[0], kh0, s, 0,0,0);
      s = __builtin_amdgcn_mfma_f32_16x16x32_bf16(qfl[1], kh1, s, 0,0,0);
      s = __builtin_amdgcn_mfma_f32_16x16x32_bf16(qfh[0], kl0, s, 0,0,0);
      s = __builtin_amdgcn_mfma_f32_16x16x32_bf16(qfh[1], kl1, s, 0,0,0);
      sf[ct]=s;
    }
    // decomposed rel-pos bias: g = floor(16*log2(ad)/log2(4097)); ad=0 -> g=0 (select, NOT ad|1).
    float mnew[4];
    #pragma unroll
    for (int r=0;r<4;++r) mnew[r]=mrow[r];
    #pragma unroll
    for (int ct=0; ct<2; ++ct){
      int j = kv0 + ct*16 + lr;
      #pragma unroll
      for (int reg=0; reg<4; ++reg){
        int rowloc = wave*16 + 4*lc + reg;
        int dd = j - (q0 + rowloc);
        int ad = dd<0 ? -dd : dd;
        int gg = ad ? (int)(__log2f((float)ad) * RCPL) : 0;
        float2 sb = ABs[rowloc][gg];
        float bias = sb.x + (dd>0 ? sb.y : (dd<0 ? -sb.y : 0.f));
        float sv = sf[ct][reg] + bias;
        sf[ct][reg] = sv;
        mnew[reg] = fmaxf(mnew[reg], sv);
      }
    }
    #pragma unroll
    for (int off=1; off<16; off<<=1){
      #pragma unroll
      for (int r=0;r<4;++r) mnew[r] = fmaxf(mnew[r], __shfl_xor(mnew[r], off, 64));
    }
    // T13 defer-max: skip rescale when max growth <= 8 (P bounded by e^8; (PO,l,m) stay consistent)
    bool okl = true;
    #pragma unroll
    for (int r=0;r<4;++r) okl = okl && (mnew[r] - mrow[r] <= 8.f);
    if (!__all(okl)){
      float scl[4];
      #pragma unroll
      for (int r=0;r<4;++r){
        scl[r] = __expf(mrow[r]-mnew[r]);
        mrow[r]=mnew[r];
        lrow[r]*=scl[r];
      }
      #pragma unroll
      for (int t12=0;t12<12;++t12){
        #pragma unroll
        for (int reg=0;reg<4;++reg) oacc[t12][reg]*=scl[reg];
      }
    }
    #pragma unroll
    for (int ct=0; ct<2; ++ct){
      #pragma unroll
      for (int reg=0; reg<4; ++reg){
        float p = __expf(sf[ct][reg]-mrow[reg]);
        lrow[reg]+=p;
        Ps[wave][4*lc+reg][ct*16+lr] = f2b(p);
      }
    }
    bf16x8 pa = *(const bf16x8*)(&Ps[wave][lr][lc*8]);
    #pragma unroll
    for (int t12=0; t12<12; ++t12){
      int vrow = t12*16 + lr;
      bf16x8 v0 = *(const bf16x8*)(&Vs[vrow][(lc ^ ((vrow>>1)&3))*8]);
      oacc[t12] = __builtin_amdgcn_mfma_f32_16x16x32_bf16(pa, v0, oacc[t12], 0,0,0);
    }
  }
  // emit partials (unnormalized O + m,l)
  #pragma unroll
  for (int off=1; off<16; off<<=1){
    #pragma unroll
    for (int r=0;r<4;++r) lrow[r] += __shfl_xor(lrow[r], off, 64);
  }
  #pragma unroll
  for (int t12=0;t12<12;++t12){
    #pragma unroll
    for (int reg=0;reg<4;++reg){
      int rowloc = wave*16 + 4*lc + reg;
      PO[((size_t)wg*64 + rowloc)*DVH + t12*16 + lr] = f2b(oacc[t12][reg]);
    }
  }
  if (lr == 0){
    #pragma unroll
    for (int reg=0; reg<4; ++reg){
      int rowloc = wave*16 + 4*lc + reg;
      ML[(size_t)wg*64 + rowloc] = make_float2(mrow[reg], lrow[reg]);
    }
  }
}

// ---------------- combine KV-split partials -> Obuf bf16 [NSEQ][HDV] ----------------
__global__ __launch_bounds__(256) void k_comb(const bf16* __restrict__ PO, const float2* __restrict__ ML,
                                              bf16* __restrict__ Obuf){
  int i = blockIdx.x;
  int qtile = i>>6, rl = i&63;
  for (int c=threadIdx.x; c<HDV; c+=256){
    int h = c/DVH, d = c - h*DVH;
    int wg0 = qtile*8 + h, wg1 = 512 + wg0;
    float2 ml0 = ML[(size_t)wg0*64 + rl];
    float2 ml1 = ML[(size_t)wg1*64 + rl];
    float M = fmaxf(ml0.x, ml1.x);
    float w0 = __expf(ml0.x - M), w1 = __expf(ml1.x - M);
    float l = ml0.y*w0 + ml1.y*w1;
    float o = b2f(PO[((size_t)wg0*64 + rl)*DVH + d])*w0
            + b2f(PO[((size_t)wg1*64 + rl)*DVH + d])*w1;
    Obuf[(size_t)i*HDV + c] = f2b(o / l);
  }
}

extern "C" void kernel_launch(void* const* d_in, const int* in_sizes, int n_in,
                              void* d_out, int out_size, void* d_ws, size_t ws_size,
                              hipStream_t stream) {
  const float* x  = (const float*)d_in[0];
  const float* lg = (const float*)d_in[1];
  const float* lb = (const float*)d_in[2];
  const float* Wq = (const float*)d_in[3];
  const float* Wk = (const float*)d_in[4];
  const float* Wv = (const float*)d_in[5];
  const float* Wr = (const float*)d_in[6];
  const float* Wo = (const float*)d_in[7];
  const float* bo = (const float*)d_in[8];
  const float* cb = (const float*)d_in[9];
  const float* pb = (const float*)d_in[10];
  float* out = (float*)d_out;

  char* ws = (char*)d_ws;
  size_t off = 0;
  auto alloc = [&](size_t bytes)->void*{ void* p = ws + off; off += (bytes + 255) & ~(size_t)255; return p; };
  // persistent through k_attn:
  bf16* WoT  = (bf16*)alloc((size_t)DIMX*HDV*2);
  bf16* qph  = (bf16*)alloc((size_t)NSEQ*HDK*2);
  bf16* qpl  = (bf16*)alloc((size_t)NSEQ*HDK*2);
  bf16* kh   = (bf16*)alloc((size_t)NSEQ*HDK*2);   // d-chunk swizzled
  bf16* kl   = (bf16*)alloc((size_t)NSEQ*HDK*2);   // d-chunk swizzled
  bf16* vt   = (bf16*)alloc((size_t)HDV*NSEQ*2);   // kv-chunk swizzled
  float* ab  = (float*)alloc((size_t)NHEAD*NSEQ*32*4);
  bf16* Obuf = (bf16*)alloc((size_t)NSEQ*HDV*2);
  float2* ML = (float2*)alloc((size_t)KSPLIT*512*64*sizeof(float2));
  // scratch (dead before k_attn) — PO aliases it:
  char* scratch = (char*)alloc(0);
  bf16* xnh  = (bf16*)alloc((size_t)NSEQ*DIMX*2);
  bf16* xnl  = (bf16*)alloc((size_t)NSEQ*DIMX*2);
  bf16* v_rm = (bf16*)alloc((size_t)NSEQ*HDV*2);
  bf16* WqT  = (bf16*)alloc((size_t)HDK*DIMX*2);
  bf16* WkT  = (bf16*)alloc((size_t)HDK*DIMX*2);
  bf16* WvT  = (bf16*)alloc((size_t)HDV*DIMX*2);
  bf16* PO   = (bf16*)scratch;   // KSPLIT*512*64*192*2 = 24 MB <= xnh+xnl
  (void)in_sizes; (void)n_in; (void)out_size; (void)ws_size;

  k_cvtT<<<dim3(HDK/32,  DIMX/32), 256, 0, stream>>>(Wq, WqT, DIMX, HDK);
  k_cvtT<<<dim3(HDK/32,  DIMX/32), 256, 0, stream>>>(Wk, WkT, DIMX, HDK);
  k_cvtT<<<dim3(HDV/32,  DIMX/32), 256, 0, stream>>>(Wv, WvT, DIMX, HDV);
  k_cvtT<<<dim3(DIMX/32, HDV/32),  256, 0, stream>>>(Wo, WoT, HDV, DIMX);
  k_ln<<<NSEQ, 256, 0, stream>>>(x, lg, lb, xnh, xnl);

  k_gemm3<1><<<(NSEQ/128)*(HDK/128), 256, 0, stream>>>(xnh, xnl, WqT, qph, qpl, cb, NSEQ, HDK, DIMX);
  k_gemm3<0><<<(NSEQ/128)*(HDK/128), 256, 0, stream>>>(xnh, xnl, WkT, kh, kl, nullptr, NSEQ, HDK, DIMX);
  k_gemm<0><<<(NSEQ/128)*(HDV/128), 256, 0, stream>>>(xnh, WvT, (void*)v_rm, nullptr, NSEQ, HDV, DIMX);

  k_abtab<<<dim3(NSEQ, NHEAD), 64, 0, stream>>>(qph, qpl, Wr, cb, pb, ab);
  k_T<<<dim3(HDV/64, NSEQ/64), 256, 0, stream>>>(v_rm, vt, NSEQ, HDV);

  k_attn<<<KSPLIT*512, 256, 0, stream>>>(qph, qpl, kh, kl, vt, ab, PO, ML);
  k_comb<<<NSEQ, 256, 0, stream>>>(PO, ML, Obuf);

  k_gemm<1><<<(NSEQ/128)*(DIMX/128), 256, 0, stream>>>(Obuf, WoT, (void*)out, bo, NSEQ, DIMX, HDV);
}

// Round 10
// 511.509 us; speedup vs baseline: 1.8659x; 1.1035x over previous
//
#include <hip/hip_runtime.h>
#include <hip/hip_bf16.h>
#include <math.h>

typedef __hip_bfloat16 bf16;
typedef __attribute__((ext_vector_type(8))) short bf16x8;
typedef __attribute__((ext_vector_type(4))) float f32x4;

#define DIMX 1536
#define NSEQ 4096
#define NHEAD 8
#define DKH 64
#define DVH 192
#define HDK 512
#define HDV 1536
#define KSPLIT 2
#define KVB 32

static __device__ __forceinline__ float b2f(bf16 x){ return __bfloat162float(x); }
static __device__ __forceinline__ bf16 f2b(float x){ return __float2bfloat16(x); }

#define GLD_TO_LDS(gsrc, ldst) __builtin_amdgcn_global_load_lds( \
    (const __attribute__((address_space(1))) unsigned int*)(gsrc), \
    (__attribute__((address_space(3))) unsigned int*)(ldst), 16, 0, 0)

// XCD-aware chunked remap (valid when gridDim.x % 8 == 0)
static __device__ __forceinline__ int xcd_swz(int b, int nwg){
  return (b & 7)*(nwg>>3) + (b>>3);
}

// ---------------- convert fp32 (K,N) -> bf16 (N,K) ----------------
__global__ __launch_bounds__(256) void k_cvtT(const float* __restrict__ W, bf16* __restrict__ WT, int K, int N){
  __shared__ float t[32][33];
  int n0 = blockIdx.x<<5, k0 = blockIdx.y<<5;
  int tx = threadIdx.x & 31, ty = threadIdx.x >> 5;
  #pragma unroll
  for (int r=ty; r<32; r+=8) t[r][tx] = W[(size_t)(k0+r)*N + n0 + tx];
  __syncthreads();
  #pragma unroll
  for (int r=ty; r<32; r+=8) WT[(size_t)(n0+r)*K + k0 + tx] = f2b(t[tx][r]);
}

// ---------------- bf16 transpose (R,C)->(C,R), kv-chunk swizzled for attn V staging ----------------
// dst (dv,kv) at kv' = (kv&~31) | (((kv>>3 & 3) ^ ((dv>>1)&3))<<3) | (kv&7)
// (dv>>1)&3 (not dv&3): Vs row stride 64B aliases banks every 2 rows (R8 fix: 4-way -> 2-way).
__global__ __launch_bounds__(256) void k_T(const bf16* __restrict__ src, bf16* __restrict__ dst, int R, int C){
  __shared__ bf16 t[64][65];
  int c0 = blockIdx.x<<6, r0 = blockIdx.y<<6;
  int tx = threadIdx.x & 63, ty = threadIdx.x >> 6;
  for (int r=ty; r<64; r+=4) t[r][tx] = src[(size_t)(r0+r)*C + c0 + tx];
  __syncthreads();
  for (int r=ty; r<64; r+=4){
    int dv = c0+r, kv = r0+tx;
    int kvp = (kv & ~31) | ((((kv>>3)&3) ^ ((dv>>1)&3))<<3) | (kv&7);
    dst[(size_t)dv*R + kvp] = t[tx][r];
  }
}

// ---------------- LayerNorm -> bf16 hi/lo ----------------
__global__ __launch_bounds__(256) void k_ln(const float* __restrict__ x, const float* __restrict__ g,
                                            const float* __restrict__ b,
                                            bf16* __restrict__ xnh, bf16* __restrict__ xnl){
  int row = blockIdx.x, t = threadIdx.x;
  const float* xr = x + (size_t)row*DIMX;
  float v[6]; float s=0.f, ss=0.f;
  #pragma unroll
  for (int j=0;j<6;++j){ v[j]=xr[t+256*j]; s+=v[j]; ss+=v[j]*v[j]; }
  int lane = t&63, wave = t>>6;
  #pragma unroll
  for (int off=32; off>0; off>>=1){ s += __shfl_down(s,off,64); ss += __shfl_down(ss,off,64); }
  __shared__ float red[8];
  if (lane==0){ red[wave]=s; red[wave+4]=ss; }
  __syncthreads();
  s = red[0]+red[1]+red[2]+red[3];
  ss = red[4]+red[5]+red[6]+red[7];
  float mu = s*(1.f/DIMX);
  float var = ss*(1.f/DIMX) - mu*mu;
  float rstd = rsqrtf(var + 1e-3f);
  #pragma unroll
  for (int j=0;j<6;++j){
    int c = t+256*j;
    float xv = (v[j]-mu)*rstd*g[c] + b[c];
    bf16 hi = f2b(xv);
    xnh[(size_t)row*DIMX + c] = hi;
    xnl[(size_t)row*DIMX + c] = f2b(xv - b2f(hi));
  }
}

// ---------------- generic bf16 MFMA GEMM ----------------
template<int EPI>
__global__ __launch_bounds__(256) void k_gemm(const bf16* __restrict__ A, const bf16* __restrict__ BT,
    void* __restrict__ Cout, const float* __restrict__ bias, int M, int N, int K)
{
  __shared__ bf16 As[128][32];
  __shared__ bf16 Bs[128][32];
  int nbx = N>>7;
  int bid = xcd_swz(blockIdx.x, gridDim.x);
  int m0 = (bid / nbx)<<7, n0 = (bid % nbx)<<7;
  int tid = threadIdx.x, wave = tid>>6, lane = tid&63;
  int lr = lane&15, lc = lane>>4;
  int wm = (wave>>1)<<6, wn = (wave&1)<<6;
  f32x4 acc[4][4] = {};
  for (int k0=0; k0<K; k0+=32){
    __syncthreads();
    #pragma unroll
    for (int it=0; it<2; ++it){
      int id = tid + (it<<8);
      int rr = id>>2, cc = id&3;
      unsigned wbase = (unsigned)(((it<<8) + (tid & 192))*16);
      GLD_TO_LDS(A  + (size_t)(m0+rr)*K + k0 + cc*8, (char*)As + wbase);
      GLD_TO_LDS(BT + (size_t)(n0+rr)*K + k0 + cc*8, (char*)Bs + wbase);
    }
    __syncthreads();
    bf16x8 af[4], bfr[4];
    #pragma unroll
    for (int mt=0; mt<4; ++mt) af[mt] = *(const bf16x8*)(&As[wm + mt*16 + lr][lc*8]);
    #pragma unroll
    for (int nt=0; nt<4; ++nt) bfr[nt] = *(const bf16x8*)(&Bs[wn + nt*16 + lr][lc*8]);
    #pragma unroll
    for (int mt=0; mt<4; ++mt)
      #pragma unroll
      for (int nt=0; nt<4; ++nt)
        acc[mt][nt] = __builtin_amdgcn_mfma_f32_16x16x32_bf16(af[mt], bfr[nt], acc[mt][nt], 0,0,0);
  }
  #pragma unroll
  for (int mt=0; mt<4; ++mt){
    #pragma unroll
    for (int nt=0; nt<4; ++nt){
      #pragma unroll
      for (int reg=0; reg<4; ++reg){
        int row = m0 + wm + mt*16 + (lc<<2) + reg;
        int col = n0 + wn + nt*16 + lr;
        if (EPI==0) ((bf16*)Cout)[(size_t)row*N + col] = f2b(acc[mt][nt][reg]);
        else        ((float*)Cout)[(size_t)row*N + col] = acc[mt][nt][reg] + bias[col];
      }
    }
  }
}

// ---------------- fused Q+K compensated GEMM: [qp|k] = (xnh+xnl) @ WqkT^T ----------------
// N=1024: cols 0-511 -> Q (scale+cb, hi/lo), cols 512-1023 -> K (d-chunk swizzled hi/lo).
// Grid = 256 blocks (fixes the 128-block grid starvation of separate Q/K GEMMs).
__global__ __launch_bounds__(256) void k_gemmqk(const bf16* __restrict__ Ahi, const bf16* __restrict__ Alo,
    const bf16* __restrict__ Bhi,
    bf16* __restrict__ qph, bf16* __restrict__ qpl,
    bf16* __restrict__ kh, bf16* __restrict__ kl, const float* __restrict__ cb)
{
  __shared__ bf16 Ash[128][32];
  __shared__ bf16 Asl[128][32];
  __shared__ bf16 Bsh[128][32];
  const int N = 1024, K = DIMX, nbx = 8;
  int bid = xcd_swz(blockIdx.x, gridDim.x);
  int m0 = (bid / nbx)<<7, n0 = (bid % nbx)<<7;
  int tid = threadIdx.x, wave = tid>>6, lane = tid&63;
  int lr = lane&15, lc = lane>>4;
  int wm = (wave>>1)<<6, wn = (wave&1)<<6;
  f32x4 acc[4][4] = {};
  for (int k0=0; k0<K; k0+=32){
    __syncthreads();
    #pragma unroll
    for (int it=0; it<2; ++it){
      int id = tid + (it<<8);
      int rr = id>>2, cc = id&3;
      unsigned wbase = (unsigned)(((it<<8) + (tid & 192))*16);
      size_t ga = (size_t)(m0+rr)*K + k0 + cc*8;
      size_t gb = (size_t)(n0+rr)*K + k0 + cc*8;
      GLD_TO_LDS(Ahi + ga, (char*)Ash + wbase);
      GLD_TO_LDS(Alo + ga, (char*)Asl + wbase);
      GLD_TO_LDS(Bhi + gb, (char*)Bsh + wbase);
    }
    __syncthreads();
    bf16x8 ah[4], al[4], bh[4];
    #pragma unroll
    for (int mt=0; mt<4; ++mt){
      ah[mt] = *(const bf16x8*)(&Ash[wm + mt*16 + lr][lc*8]);
      al[mt] = *(const bf16x8*)(&Asl[wm + mt*16 + lr][lc*8]);
    }
    #pragma unroll
    for (int nt=0; nt<4; ++nt)
      bh[nt] = *(const bf16x8*)(&Bsh[wn + nt*16 + lr][lc*8]);
    #pragma unroll
    for (int mt=0; mt<4; ++mt)
      #pragma unroll
      for (int nt=0; nt<4; ++nt){
        acc[mt][nt] = __builtin_amdgcn_mfma_f32_16x16x32_bf16(ah[mt], bh[nt], acc[mt][nt], 0,0,0);
        acc[mt][nt] = __builtin_amdgcn_mfma_f32_16x16x32_bf16(al[mt], bh[nt], acc[mt][nt], 0,0,0);
      }
  }
  bool isQ = (n0 < 512);
  #pragma unroll
  for (int mt=0; mt<4; ++mt){
    #pragma unroll
    for (int nt=0; nt<4; ++nt){
      #pragma unroll
      for (int reg=0; reg<4; ++reg){
        int row = m0 + wm + mt*16 + (lc<<2) + reg;
        int col = n0 + wn + nt*16 + lr;
        float v = acc[mt][nt][reg];
        if (isQ){
          v = v*0.125f + cb[col];
          bf16 hi = f2b(v);
          qph[(size_t)row*HDK + col] = hi;
          qpl[(size_t)row*HDK + col] = f2b(v - b2f(hi));
        } else {
          int ck = col - 512;
          int colw = (ck & ~63) | ((((ck>>3)&7) ^ (row&7))<<3) | (ck&7);
          bf16 hi = f2b(v);
          kh[(size_t)row*HDK + colw] = hi;
          kl[(size_t)row*HDK + colw] = f2b(v - b2f(hi));
        }
      }
    }
  }
}

// ---------------- per i (all h): u = Wr_h^T (qp - cb + pb); emit Tpos/Tneg tables ----------------
// ab layout: [h][i][34]: [0..15]=Tpos=A+B, [16]=A[0] (dd==0), [17..32]=Tneg=A-B, [33]=A[0].
__global__ __launch_bounds__(256) void k_abtab(const bf16* __restrict__ qph, const bf16* __restrict__ qpl,
                                               const float* __restrict__ Wr,
                                               const float* __restrict__ cb, const float* __restrict__ pb,
                                               float* __restrict__ ab){
  int i = blockIdx.x, t = threadIdx.x;
  __shared__ float qpp[HDK];
  __shared__ float us[NHEAD][32];
  #pragma unroll
  for (int j=0;j<2;++j){
    int c = t + j*256;
    size_t qi = (size_t)i*HDK + c;
    qpp[c] = b2f(qph[qi]) + b2f(qpl[qi]) - cb[c] + pb[c];
  }
  __syncthreads();
  {
    int h = t>>5, f = t&31;
    const float* wr = Wr + (size_t)f*HDK + h*DKH;
    const float* qh = qpp + h*DKH;
    float u = 0.f;
    #pragma unroll
    for (int d=0; d<64; d+=4){
      float4 w4 = *(const float4*)(wr + d);
      u += w4.x*qh[d] + w4.y*qh[d+1] + w4.z*qh[d+2] + w4.w*qh[d+3];
    }
    us[h][f] = u;
  }
  __syncthreads();
  if (t < 128){
    int h2 = t>>4, f2 = t&15;
    float a=0.f, bb=0.f;
    for (int g=15; g>=f2; --g){ a += us[h2][g]; bb += us[h2][16+g]; }
    float* o = ab + ((size_t)h2*NSEQ + i)*34;
    o[f2] = a + bb;
    o[17+f2] = a - bb;
    if (f2 == 0){ o[16] = a; o[33] = a; }
  }
}

// ---------------- flash attention, KV-split, LDS-staged, defer-max, Tpos/Tneg bias ----------------
__global__ __launch_bounds__(256,4) void k_attn(
    const bf16* __restrict__ qph, const bf16* __restrict__ qpl,
    const bf16* __restrict__ khs, const bf16* __restrict__ kls,
    const bf16* __restrict__ vts, const float* __restrict__ ab,
    bf16* __restrict__ PO, float2* __restrict__ ML)
{
  int wg = blockIdx.x;
  int h  = wg & 7;
  int qtile = (wg >> 3) & 63;
  int ks = wg >> 9;
  int q0 = qtile * 64;
  int tid = threadIdx.x, wave = tid>>6, lane = tid&63;
  int lr = lane&15, lc = lane>>4;

  __shared__ bf16 Ksh[KVB][64];    // chunk^(row&7) swizzle (pre-swizzled in global)
  __shared__ bf16 Ksl[KVB][64];
  __shared__ bf16 Vs[DVH][KVB];    // chunk^((dv>>1)&3) swizzle (pre-swizzled in global)
  __shared__ bf16 Ps[4][16][36];
  __shared__ float Ts[64][34];     // [row][0..16]=Tpos+A0, [17..33]=Tneg+A0

  {
    const float* src = ab + ((size_t)h*NSEQ + q0)*34;
    for (int xx=tid; xx<64*34; xx+=256) ((float*)Ts)[xx] = src[xx];
  }

  bf16x8 qfh[2], qfl[2];
  {
    int row = q0 + wave*16 + lr;
    const bf16* qrh = qph + (size_t)row*HDK + h*DKH;
    const bf16* qrl = qpl + (size_t)row*HDK + h*DKH;
    qfh[0] = *(const bf16x8*)(qrh + 8*lc);
    qfh[1] = *(const bf16x8*)(qrh + 32 + 8*lc);
    qfl[0] = *(const bf16x8*)(qrl + 8*lc);
    qfl[1] = *(const bf16x8*)(qrl + 32 + 8*lc);
  }
  const bf16* Kh = khs + h*DKH;
  const bf16* Kl = kls + h*DKH;
  const bf16* Vt = vts + (size_t)h*DVH*NSEQ;

  f32x4 oacc[12] = {};
  float mrow[4], lrow[4];
  #pragma unroll
  for (int r=0;r<4;++r){ mrow[r]=-3e38f; lrow[r]=0.f; }

  const float RCPL = 1.33329424f;  // 16 / log2(4097)
  int kv_lo = ks * (NSEQ/KSPLIT);
  int kv_hi = kv_lo + NSEQ/KSPLIT;

  for (int kv0=kv_lo; kv0<kv_hi; kv0+=KVB) {
    __syncthreads();
    {
      int r = tid>>3, c = tid&7;
      size_t gk = (size_t)(kv0+r)*HDK + c*8;
      GLD_TO_LDS(Kh + gk, (char*)Ksh + (tid&192)*16);
      GLD_TO_LDS(Kl + gk, (char*)Ksl + (tid&192)*16);
      #pragma unroll
      for (int j=0; j<3; ++j){
        int id = j*256 + tid;
        int vr = id>>2, vc = id&3;
        GLD_TO_LDS(Vt + (size_t)vr*NSEQ + kv0 + vc*8, (char*)Vs + (j*256 + (tid&192))*16);
      }
    }
    __syncthreads();

    f32x4 sf[2];
    #pragma unroll
    for (int ct=0; ct<2; ++ct){
      f32x4 s = {};
      int krow = ct*16 + lr;
      int sw0 = ((lc  ) ^ (krow&7))*8;
      int sw1 = ((lc+4) ^ (krow&7))*8;
      bf16x8 kh0 = *(const bf16x8*)(&Ksh[krow][sw0]);
      bf16x8 kh1 = *(const bf16x8*)(&Ksh[krow][sw1]);
      bf16x8 kl0 = *(const bf16x8*)(&Ksl[krow][sw0]);
      bf16x8 kl1 = *(const bf16x8*)(&Ksl[krow][sw1]);
      s = __builtin_amdgcn_mfma_f32_16x16x32_bf16(qfh[0], kh0, s, 0,0,0);
      s = __builtin_amdgcn_mfma_f32_16x16x32_bf16(qfh[1], kh1, s, 0,0,0);
      s = __builtin_amdgcn_mfma_f32_16x16x32_bf16(qfl[0], kh0, s, 0,0,0);
      s = __builtin_amdgcn_mfma_f32_16x16x32_bf16(qfl[1], kh1, s, 0,0,0);
      s = __builtin_amdgcn_mfma_f32_16x16x32_bf16(qfh[0], kl0, s, 0,0,0);
      s = __builtin_amdgcn_mfma_f32_16x16x32_bf16(qfh[1], kl1, s, 0,0,0);
      sf[ct]=s;
    }
    // bias: gg = floor(16*log2(ad)/log2(4097)); ad==0 -> slot 16; dd<0 -> +17 (Tneg).
    float mnew[4];
    #pragma unroll
    for (int r=0;r<4;++r) mnew[r]=mrow[r];
    #pragma unroll
    for (int ct=0; ct<2; ++ct){
      int j = kv0 + ct*16 + lr;
      #pragma unroll
      for (int reg=0; reg<4; ++reg){
        int rowloc = wave*16 + 4*lc + reg;
        int dd = j - (q0 + rowloc);
        int ad = dd<0 ? -dd : dd;
        int gg = ad ? (int)(__log2f((float)ad) * RCPL) : 16;
        float bias = Ts[rowloc][(dd<0 ? 17:0) + gg];
        float sv = sf[ct][reg] + bias;
        sf[ct][reg] = sv;
        mnew[reg] = fmaxf(mnew[reg], sv);
      }
    }
    #pragma unroll
    for (int off=1; off<16; off<<=1){
      #pragma unroll
      for (int r=0;r<4;++r) mnew[r] = fmaxf(mnew[r], __shfl_xor(mnew[r], off, 64));
    }
    bool okl = true;
    #pragma unroll
    for (int r=0;r<4;++r) okl = okl && (mnew[r] - mrow[r] <= 8.f);
    if (!__all(okl)){
      float scl[4];
      #pragma unroll
      for (int r=0;r<4;++r){
        scl[r] = __expf(mrow[r]-mnew[r]);
        mrow[r]=mnew[r];
        lrow[r]*=scl[r];
      }
      #pragma unroll
      for (int t12=0;t12<12;++t12){
        #pragma unroll
        for (int reg=0;reg<4;++reg) oacc[t12][reg]*=scl[reg];
      }
    }
    #pragma unroll
    for (int ct=0; ct<2; ++ct){
      #pragma unroll
      for (int reg=0; reg<4; ++reg){
        float p = __expf(sf[ct][reg]-mrow[reg]);
        lrow[reg]+=p;
        Ps[wave][4*lc+reg][ct*16+lr] = f2b(p);
      }
    }
    bf16x8 pa = *(const bf16x8*)(&Ps[wave][lr][lc*8]);
    #pragma unroll
    for (int t12=0; t12<12; ++t12){
      int vrow = t12*16 + lr;
      bf16x8 v0 = *(const bf16x8*)(&Vs[vrow][(lc ^ ((vrow>>1)&3))*8]);
      oacc[t12] = __builtin_amdgcn_mfma_f32_16x16x32_bf16(pa, v0, oacc[t12], 0,0,0);
    }
  }
  #pragma unroll
  for (int off=1; off<16; off<<=1){
    #pragma unroll
    for (int r=0;r<4;++r) lrow[r] += __shfl_xor(lrow[r], off, 64);
  }
  #pragma unroll
  for (int t12=0;t12<12;++t12){
    #pragma unroll
    for (int reg=0;reg<4;++reg){
      int rowloc = wave*16 + 4*lc + reg;
      PO[((size_t)wg*64 + rowloc)*DVH + t12*16 + lr] = f2b(oacc[t12][reg]);
    }
  }
  if (lr == 0){
    #pragma unroll
    for (int reg=0; reg<4; ++reg){
      int rowloc = wave*16 + 4*lc + reg;
      ML[(size_t)wg*64 + rowloc] = make_float2(mrow[reg], lrow[reg]);
    }
  }
}

// ---------------- combine KV-split partials -> Obuf bf16 [NSEQ][HDV] ----------------
__global__ __launch_bounds__(256) void k_comb(const bf16* __restrict__ PO, const float2* __restrict__ ML,
                                              bf16* __restrict__ Obuf){
  int i = blockIdx.x;
  int qtile = i>>6, rl = i&63;
  for (int c=threadIdx.x; c<HDV; c+=256){
    int h = c/DVH, d = c - h*DVH;
    int wg0 = qtile*8 + h, wg1 = 512 + wg0;
    float2 ml0 = ML[(size_t)wg0*64 + rl];
    float2 ml1 = ML[(size_t)wg1*64 + rl];
    float M = fmaxf(ml0.x, ml1.x);
    float w0 = __expf(ml0.x - M), w1 = __expf(ml1.x - M);
    float l = ml0.y*w0 + ml1.y*w1;
    float o = b2f(PO[((size_t)wg0*64 + rl)*DVH + d])*w0
            + b2f(PO[((size_t)wg1*64 + rl)*DVH + d])*w1;
    Obuf[(size_t)i*HDV + c] = f2b(o / l);
  }
}

extern "C" void kernel_launch(void* const* d_in, const int* in_sizes, int n_in,
                              void* d_out, int out_size, void* d_ws, size_t ws_size,
                              hipStream_t stream) {
  const float* x  = (const float*)d_in[0];
  const float* lg = (const float*)d_in[1];
  const float* lb = (const float*)d_in[2];
  const float* Wq = (const float*)d_in[3];
  const float* Wk = (const float*)d_in[4];
  const float* Wv = (const float*)d_in[5];
  const float* Wr = (const float*)d_in[6];
  const float* Wo = (const float*)d_in[7];
  const float* bo = (const float*)d_in[8];
  const float* cb = (const float*)d_in[9];
  const float* pb = (const float*)d_in[10];
  float* out = (float*)d_out;

  char* ws = (char*)d_ws;
  size_t off = 0;
  auto alloc = [&](size_t bytes)->void*{ void* p = ws + off; off += (bytes + 255) & ~(size_t)255; return p; };
  // persistent through k_attn:
  bf16* WoT  = (bf16*)alloc((size_t)DIMX*HDV*2);
  bf16* qph  = (bf16*)alloc((size_t)NSEQ*HDK*2);
  bf16* qpl  = (bf16*)alloc((size_t)NSEQ*HDK*2);
  bf16* kh   = (bf16*)alloc((size_t)NSEQ*HDK*2);   // d-chunk swizzled
  bf16* kl   = (bf16*)alloc((size_t)NSEQ*HDK*2);   // d-chunk swizzled
  bf16* vt   = (bf16*)alloc((size_t)HDV*NSEQ*2);   // kv-chunk swizzled
  float* ab  = (float*)alloc((size_t)NHEAD*NSEQ*34*4);
  bf16* Obuf = (bf16*)alloc((size_t)NSEQ*HDV*2);
  float2* ML = (float2*)alloc((size_t)KSPLIT*512*64*sizeof(float2));
  // scratch (dead before k_attn) — PO aliases it:
  char* scratch = (char*)alloc(0);
  bf16* xnh  = (bf16*)alloc((size_t)NSEQ*DIMX*2);
  bf16* xnl  = (bf16*)alloc((size_t)NSEQ*DIMX*2);
  bf16* v_rm = (bf16*)alloc((size_t)NSEQ*HDV*2);
  bf16* WqkT = (bf16*)alloc((size_t)1024*DIMX*2);
  bf16* WvT  = (bf16*)alloc((size_t)HDV*DIMX*2);
  bf16* PO   = (bf16*)scratch;   // KSPLIT*512*64*192*2 = 24 MB <= xnh+xnl
  (void)in_sizes; (void)n_in; (void)out_size; (void)ws_size;

  k_cvtT<<<dim3(HDK/32,  DIMX/32), 256, 0, stream>>>(Wq, WqkT, DIMX, HDK);
  k_cvtT<<<dim3(HDK/32,  DIMX/32), 256, 0, stream>>>(Wk, WqkT + (size_t)512*DIMX, DIMX, HDK);
  k_cvtT<<<dim3(HDV/32,  DIMX/32), 256, 0, stream>>>(Wv, WvT, DIMX, HDV);
  k_cvtT<<<dim3(DIMX/32, HDV/32),  256, 0, stream>>>(Wo, WoT, HDV, DIMX);
  k_ln<<<NSEQ, 256, 0, stream>>>(x, lg, lb, xnh, xnl);

  k_gemmqk<<<(NSEQ/128)*(1024/128), 256, 0, stream>>>(xnh, xnl, WqkT, qph, qpl, kh, kl, cb);
  k_gemm<0><<<(NSEQ/128)*(HDV/128), 256, 0, stream>>>(xnh, WvT, (void*)v_rm, nullptr, NSEQ, HDV, DIMX);

  k_abtab<<<NSEQ, 256, 0, stream>>>(qph, qpl, Wr, cb, pb, ab);
  k_T<<<dim3(HDV/64, NSEQ/64), 256, 0, stream>>>(v_rm, vt, NSEQ, HDV);

  k_attn<<<KSPLIT*512, 256, 0, stream>>>(qph, qpl, kh, kl, vt, ab, PO, ML);
  k_comb<<<NSEQ, 256, 0, stream>>>(PO, ML, Obuf);

  k_gemm<1><<<(NSEQ/128)*(DIMX/128), 256, 0, stream>>>(Obuf, WoT, (void*)out, bo, NSEQ, DIMX, HDV);
}

// Round 11
// 496.977 us; speedup vs baseline: 1.9205x; 1.0292x over previous
//
#include <hip/hip_runtime.h>
#include <hip/hip_bf16.h>
#include <math.h>

typedef __hip_bfloat16 bf16;
typedef __attribute__((ext_vector_type(8))) short bf16x8;
typedef __attribute__((ext_vector_type(4))) float f32x4;

#define DIMX 1536
#define NSEQ 4096
#define NHEAD 8
#define DKH 64
#define DVH 192
#define HDK 512
#define HDV 1536
#define KSPLIT 2
#define KVB 32

static __device__ __forceinline__ float b2f(bf16 x){ return __bfloat162float(x); }
static __device__ __forceinline__ bf16 f2b(float x){ return __float2bfloat16(x); }

#define GLD_TO_LDS(gsrc, ldst) __builtin_amdgcn_global_load_lds( \
    (const __attribute__((address_space(1))) unsigned int*)(gsrc), \
    (__attribute__((address_space(3))) unsigned int*)(ldst), 16, 0, 0)

// XCD-aware chunked remap (valid when gridDim.x % 8 == 0)
static __device__ __forceinline__ int xcd_swz(int b, int nwg){
  return (b & 7)*(nwg>>3) + (b>>3);
}

// ---------------- convert fp32 (K,N) -> bf16 (N,K) ----------------
__global__ __launch_bounds__(256) void k_cvtT(const float* __restrict__ W, bf16* __restrict__ WT, int K, int N){
  __shared__ float t[32][33];
  int n0 = blockIdx.x<<5, k0 = blockIdx.y<<5;
  int tx = threadIdx.x & 31, ty = threadIdx.x >> 5;
  #pragma unroll
  for (int r=ty; r<32; r+=8) t[r][tx] = W[(size_t)(k0+r)*N + n0 + tx];
  __syncthreads();
  #pragma unroll
  for (int r=ty; r<32; r+=8) WT[(size_t)(n0+r)*K + k0 + tx] = f2b(t[tx][r]);
}

// ---------------- bf16 transpose (R,C)->(C,R), kv-chunk swizzled for attn V staging ----------------
// dst (dv,kv) at kv' = (kv&~31) | (((kv>>3 & 3) ^ ((dv>>1)&3))<<3) | (kv&7)
// (dv>>1)&3 (not dv&3): Vs row stride 64B aliases banks every 2 rows (R8 fix: 4-way -> 2-way).
__global__ __launch_bounds__(256) void k_T(const bf16* __restrict__ src, bf16* __restrict__ dst, int R, int C){
  __shared__ bf16 t[64][65];
  int c0 = blockIdx.x<<6, r0 = blockIdx.y<<6;
  int tx = threadIdx.x & 63, ty = threadIdx.x >> 6;
  for (int r=ty; r<64; r+=4) t[r][tx] = src[(size_t)(r0+r)*C + c0 + tx];
  __syncthreads();
  for (int r=ty; r<64; r+=4){
    int dv = c0+r, kv = r0+tx;
    int kvp = (kv & ~31) | ((((kv>>3)&3) ^ ((dv>>1)&3))<<3) | (kv&7);
    dst[(size_t)dv*R + kvp] = t[tx][r];
  }
}

// ---------------- LayerNorm -> bf16 hi/lo ----------------
__global__ __launch_bounds__(256) void k_ln(const float* __restrict__ x, const float* __restrict__ g,
                                            const float* __restrict__ b,
                                            bf16* __restrict__ xnh, bf16* __restrict__ xnl){
  int row = blockIdx.x, t = threadIdx.x;
  const float* xr = x + (size_t)row*DIMX;
  float v[6]; float s=0.f, ss=0.f;
  #pragma unroll
  for (int j=0;j<6;++j){ v[j]=xr[t+256*j]; s+=v[j]; ss+=v[j]*v[j]; }
  int lane = t&63, wave = t>>6;
  #pragma unroll
  for (int off=32; off>0; off>>=1){ s += __shfl_down(s,off,64); ss += __shfl_down(ss,off,64); }
  __shared__ float red[8];
  if (lane==0){ red[wave]=s; red[wave+4]=ss; }
  __syncthreads();
  s = red[0]+red[1]+red[2]+red[3];
  ss = red[4]+red[5]+red[6]+red[7];
  float mu = s*(1.f/DIMX);
  float var = ss*(1.f/DIMX) - mu*mu;
  float rstd = rsqrtf(var + 1e-3f);
  #pragma unroll
  for (int j=0;j<6;++j){
    int c = t+256*j;
    float xv = (v[j]-mu)*rstd*g[c] + b[c];
    bf16 hi = f2b(xv);
    xnh[(size_t)row*DIMX + c] = hi;
    xnl[(size_t)row*DIMX + c] = f2b(xv - b2f(hi));
  }
}

// ---------------- generic bf16 MFMA GEMM ----------------
template<int EPI>
__global__ __launch_bounds__(256) void k_gemm(const bf16* __restrict__ A, const bf16* __restrict__ BT,
    void* __restrict__ Cout, const float* __restrict__ bias, int M, int N, int K)
{
  __shared__ bf16 As[128][32];
  __shared__ bf16 Bs[128][32];
  int nbx = N>>7;
  int bid = xcd_swz(blockIdx.x, gridDim.x);
  int m0 = (bid / nbx)<<7, n0 = (bid % nbx)<<7;
  int tid = threadIdx.x, wave = tid>>6, lane = tid&63;
  int lr = lane&15, lc = lane>>4;
  int wm = (wave>>1)<<6, wn = (wave&1)<<6;
  f32x4 acc[4][4] = {};
  for (int k0=0; k0<K; k0+=32){
    __syncthreads();
    #pragma unroll
    for (int it=0; it<2; ++it){
      int id = tid + (it<<8);
      int rr = id>>2, cc = id&3;
      unsigned wbase = (unsigned)(((it<<8) + (tid & 192))*16);
      GLD_TO_LDS(A  + (size_t)(m0+rr)*K + k0 + cc*8, (char*)As + wbase);
      GLD_TO_LDS(BT + (size_t)(n0+rr)*K + k0 + cc*8, (char*)Bs + wbase);
    }
    __syncthreads();
    bf16x8 af[4], bfr[4];
    #pragma unroll
    for (int mt=0; mt<4; ++mt) af[mt] = *(const bf16x8*)(&As[wm + mt*16 + lr][lc*8]);
    #pragma unroll
    for (int nt=0; nt<4; ++nt) bfr[nt] = *(const bf16x8*)(&Bs[wn + nt*16 + lr][lc*8]);
    #pragma unroll
    for (int mt=0; mt<4; ++mt)
      #pragma unroll
      for (int nt=0; nt<4; ++nt)
        acc[mt][nt] = __builtin_amdgcn_mfma_f32_16x16x32_bf16(af[mt], bfr[nt], acc[mt][nt], 0,0,0);
  }
  #pragma unroll
  for (int mt=0; mt<4; ++mt){
    #pragma unroll
    for (int nt=0; nt<4; ++nt){
      #pragma unroll
      for (int reg=0; reg<4; ++reg){
        int row = m0 + wm + mt*16 + (lc<<2) + reg;
        int col = n0 + wn + nt*16 + lr;
        if (EPI==0) ((bf16*)Cout)[(size_t)row*N + col] = f2b(acc[mt][nt][reg]);
        else        ((float*)Cout)[(size_t)row*N + col] = acc[mt][nt][reg] + bias[col];
      }
    }
  }
}

// ---------------- fused Q+K compensated GEMM: [qp|k] = (xnh+xnl) @ WqkT^T ----------------
__global__ __launch_bounds__(256) void k_gemmqk(const bf16* __restrict__ Ahi, const bf16* __restrict__ Alo,
    const bf16* __restrict__ Bhi,
    bf16* __restrict__ qph, bf16* __restrict__ qpl,
    bf16* __restrict__ kh, bf16* __restrict__ kl, const float* __restrict__ cb)
{
  __shared__ bf16 Ash[128][32];
  __shared__ bf16 Asl[128][32];
  __shared__ bf16 Bsh[128][32];
  const int N = 1024, K = DIMX, nbx = 8;
  int bid = xcd_swz(blockIdx.x, gridDim.x);
  int m0 = (bid / nbx)<<7, n0 = (bid % nbx)<<7;
  int tid = threadIdx.x, wave = tid>>6, lane = tid&63;
  int lr = lane&15, lc = lane>>4;
  int wm = (wave>>1)<<6, wn = (wave&1)<<6;
  f32x4 acc[4][4] = {};
  for (int k0=0; k0<K; k0+=32){
    __syncthreads();
    #pragma unroll
    for (int it=0; it<2; ++it){
      int id = tid + (it<<8);
      int rr = id>>2, cc = id&3;
      unsigned wbase = (unsigned)(((it<<8) + (tid & 192))*16);
      size_t ga = (size_t)(m0+rr)*K + k0 + cc*8;
      size_t gb = (size_t)(n0+rr)*K + k0 + cc*8;
      GLD_TO_LDS(Ahi + ga, (char*)Ash + wbase);
      GLD_TO_LDS(Alo + ga, (char*)Asl + wbase);
      GLD_TO_LDS(Bhi + gb, (char*)Bsh + wbase);
    }
    __syncthreads();
    bf16x8 ah[4], al[4], bh[4];
    #pragma unroll
    for (int mt=0; mt<4; ++mt){
      ah[mt] = *(const bf16x8*)(&Ash[wm + mt*16 + lr][lc*8]);
      al[mt] = *(const bf16x8*)(&Asl[wm + mt*16 + lr][lc*8]);
    }
    #pragma unroll
    for (int nt=0; nt<4; ++nt)
      bh[nt] = *(const bf16x8*)(&Bsh[wn + nt*16 + lr][lc*8]);
    #pragma unroll
    for (int mt=0; mt<4; ++mt)
      #pragma unroll
      for (int nt=0; nt<4; ++nt){
        acc[mt][nt] = __builtin_amdgcn_mfma_f32_16x16x32_bf16(ah[mt], bh[nt], acc[mt][nt], 0,0,0);
        acc[mt][nt] = __builtin_amdgcn_mfma_f32_16x16x32_bf16(al[mt], bh[nt], acc[mt][nt], 0,0,0);
      }
  }
  bool isQ = (n0 < 512);
  #pragma unroll
  for (int mt=0; mt<4; ++mt){
    #pragma unroll
    for (int nt=0; nt<4; ++nt){
      #pragma unroll
      for (int reg=0; reg<4; ++reg){
        int row = m0 + wm + mt*16 + (lc<<2) + reg;
        int col = n0 + wn + nt*16 + lr;
        float v = acc[mt][nt][reg];
        if (isQ){
          v = v*0.125f + cb[col];
          bf16 hi = f2b(v);
          qph[(size_t)row*HDK + col] = hi;
          qpl[(size_t)row*HDK + col] = f2b(v - b2f(hi));
        } else {
          int ck = col - 512;
          int colw = (ck & ~63) | ((((ck>>3)&7) ^ (row&7))<<3) | (ck&7);
          bf16 hi = f2b(v);
          kh[(size_t)row*HDK + colw] = hi;
          kl[(size_t)row*HDK + colw] = f2b(v - b2f(hi));
        }
      }
    }
  }
}

// ---------------- per i (all h): u = Wr_h^T (qp - cb + pb); emit Tpos/Tneg tables ----------------
// ab layout: [h][i][34]: [0..15]=Tpos=A+B, [16]=A[0] (dd==0), [17..32]=Tneg=A-B, [33]=A[0].
__global__ __launch_bounds__(256) void k_abtab(const bf16* __restrict__ qph, const bf16* __restrict__ qpl,
                                               const float* __restrict__ Wr,
                                               const float* __restrict__ cb, const float* __restrict__ pb,
                                               float* __restrict__ ab){
  int i = blockIdx.x, t = threadIdx.x;
  __shared__ float qpp[HDK];
  __shared__ float us[NHEAD][32];
  #pragma unroll
  for (int j=0;j<2;++j){
    int c = t + j*256;
    size_t qi = (size_t)i*HDK + c;
    qpp[c] = b2f(qph[qi]) + b2f(qpl[qi]) - cb[c] + pb[c];
  }
  __syncthreads();
  {
    int h = t>>5, f = t&31;
    const float* wr = Wr + (size_t)f*HDK + h*DKH;
    const float* qh = qpp + h*DKH;
    float u = 0.f;
    #pragma unroll
    for (int d=0; d<64; d+=4){
      float4 w4 = *(const float4*)(wr + d);
      u += w4.x*qh[d] + w4.y*qh[d+1] + w4.z*qh[d+2] + w4.w*qh[d+3];
    }
    us[h][f] = u;
  }
  __syncthreads();
  if (t < 128){
    int h2 = t>>4, f2 = t&15;
    float a=0.f, bb=0.f;
    for (int g=15; g>=f2; --g){ a += us[h2][g]; bb += us[h2][16+g]; }
    float* o = ab + ((size_t)h2*NSEQ + i)*34;
    o[f2] = a + bb;
    o[17+f2] = a - bb;
    if (f2 == 0){ o[16] = a; o[33] = a; }
  }
}

// ---------------- flash attention, KV-split, LDS-staged, defer-max, uniform-band fast path ----------------
__global__ __launch_bounds__(256,4) void k_attn(
    const bf16* __restrict__ qph, const bf16* __restrict__ qpl,
    const bf16* __restrict__ khs, const bf16* __restrict__ kls,
    const bf16* __restrict__ vts, const float* __restrict__ ab,
    bf16* __restrict__ PO, float2* __restrict__ ML)
{
  int wg = blockIdx.x;
  int h  = wg & 7;
  int qtile = (wg >> 3) & 63;
  int ks = wg >> 9;
  int q0 = qtile * 64;
  int tid = threadIdx.x, wave = tid>>6, lane = tid&63;
  int lr = lane&15, lc = lane>>4;

  __shared__ bf16 Ksh[KVB][64];    // chunk^(row&7) swizzle (pre-swizzled in global)
  __shared__ bf16 Ksl[KVB][64];
  __shared__ bf16 Vs[DVH][KVB];    // chunk^((dv>>1)&3) swizzle (pre-swizzled in global)
  __shared__ bf16 Ps[4][16][36];
  __shared__ float Ts[64][34];     // [row][0..16]=Tpos+A0, [17..33]=Tneg+A0

  {
    const float* src = ab + ((size_t)h*NSEQ + q0)*34;
    for (int xx=tid; xx<64*34; xx+=256) ((float*)Ts)[xx] = src[xx];
  }

  bf16x8 qfh[2], qfl[2];
  {
    int row = q0 + wave*16 + lr;
    const bf16* qrh = qph + (size_t)row*HDK + h*DKH;
    const bf16* qrl = qpl + (size_t)row*HDK + h*DKH;
    qfh[0] = *(const bf16x8*)(qrh + 8*lc);
    qfh[1] = *(const bf16x8*)(qrh + 32 + 8*lc);
    qfl[0] = *(const bf16x8*)(qrl + 8*lc);
    qfl[1] = *(const bf16x8*)(qrl + 32 + 8*lc);
  }
  const bf16* Kh = khs + h*DKH;
  const bf16* Kl = kls + h*DKH;
  const bf16* Vt = vts + (size_t)h*DVH*NSEQ;

  f32x4 oacc[12] = {};
  float mrow[4], lrow[4];
  #pragma unroll
  for (int r=0;r<4;++r){ mrow[r]=-3e38f; lrow[r]=0.f; }

  const float RCPL = 1.33329424f;  // 16 / log2(4097)
  int kv_lo = ks * (NSEQ/KSPLIT);
  int kv_hi = kv_lo + NSEQ/KSPLIT;

  for (int kv0=kv_lo; kv0<kv_hi; kv0+=KVB) {
    __syncthreads();
    {
      int r = tid>>3, c = tid&7;
      size_t gk = (size_t)(kv0+r)*HDK + c*8;
      GLD_TO_LDS(Kh + gk, (char*)Ksh + (tid&192)*16);
      GLD_TO_LDS(Kl + gk, (char*)Ksl + (tid&192)*16);
      #pragma unroll
      for (int j=0; j<3; ++j){
        int id = j*256 + tid;
        int vr = id>>2, vc = id&3;
        GLD_TO_LDS(Vt + (size_t)vr*NSEQ + kv0 + vc*8, (char*)Vs + (j*256 + (tid&192))*16);
      }
    }
    __syncthreads();

    f32x4 sf[2];
    #pragma unroll
    for (int ct=0; ct<2; ++ct){
      f32x4 s = {};
      int krow = ct*16 + lr;
      int sw0 = ((lc  ) ^ (krow&7))*8;
      int sw1 = ((lc+4) ^ (krow&7))*8;
      bf16x8 kh0 = *(const bf16x8*)(&Ksh[krow][sw0]);
      bf16x8 kh1 = *(const bf16x8*)(&Ksh[krow][sw1]);
      bf16x8 kl0 = *(const bf16x8*)(&Ksl[krow][sw0]);
      bf16x8 kl1 = *(const bf16x8*)(&Ksl[krow][sw1]);
      s = __builtin_amdgcn_mfma_f32_16x16x32_bf16(qfh[0], kh0, s, 0,0,0);
      s = __builtin_amdgcn_mfma_f32_16x16x32_bf16(qfh[1], kh1, s, 0,0,0);
      s = __builtin_amdgcn_mfma_f32_16x16x32_bf16(qfl[0], kh0, s, 0,0,0);
      s = __builtin_amdgcn_mfma_f32_16x16x32_bf16(qfl[1], kh1, s, 0,0,0);
      s = __builtin_amdgcn_mfma_f32_16x16x32_bf16(qfh[0], kl0, s, 0,0,0);
      s = __builtin_amdgcn_mfma_f32_16x16x32_bf16(qfh[1], kl1, s, 0,0,0);
      sf[ct]=s;
    }
    // ---- rel-pos bias ----
    // Fast path: whole tile one sign + one log-band (true for ~80% of tiles; |d|>=182
    // guarantees band width >= tile dd-range of 95). Bit-identical to slow path.
    int tmin = kv0 - q0 - 63, tmax = kv0 - q0 + 31;   // dd range of this tile
    int slotu = -1;
    if (tmin >= 1){
      int g1 = (int)(__log2f((float)tmin) * RCPL);
      int g2 = (int)(__log2f((float)tmax) * RCPL);
      if (g1 == g2) slotu = g1;
    } else if (tmax <= -1){
      int g1 = (int)(__log2f((float)(-tmax)) * RCPL);
      int g2 = (int)(__log2f((float)(-tmin)) * RCPL);
      if (g1 == g2) slotu = 17 + g1;
    }
    float mnew[4];
    #pragma unroll
    for (int r=0;r<4;++r) mnew[r]=mrow[r];
    if (slotu >= 0){
      float bu[4];
      #pragma unroll
      for (int reg=0; reg<4; ++reg) bu[reg] = Ts[wave*16 + 4*lc + reg][slotu];
      #pragma unroll
      for (int ct=0; ct<2; ++ct){
        #pragma unroll
        for (int reg=0; reg<4; ++reg){
          float sv = sf[ct][reg] + bu[reg];
          sf[ct][reg] = sv;
          mnew[reg] = fmaxf(mnew[reg], sv);
        }
      }
    } else {
      // general path: gg = floor(16*log2(ad)/log2(4097)); ad==0 -> slot 16; dd<0 -> +17.
      #pragma unroll
      for (int ct=0; ct<2; ++ct){
        int j = kv0 + ct*16 + lr;
        #pragma unroll
        for (int reg=0; reg<4; ++reg){
          int rowloc = wave*16 + 4*lc + reg;
          int dd = j - (q0 + rowloc);
          int ad = dd<0 ? -dd : dd;
          int gg = ad ? (int)(__log2f((float)ad) * RCPL) : 16;
          float bias = Ts[rowloc][(dd<0 ? 17:0) + gg];
          float sv = sf[ct][reg] + bias;
          sf[ct][reg] = sv;
          mnew[reg] = fmaxf(mnew[reg], sv);
        }
      }
    }
    #pragma unroll
    for (int off=1; off<16; off<<=1){
      #pragma unroll
      for (int r=0;r<4;++r) mnew[r] = fmaxf(mnew[r], __shfl_xor(mnew[r], off, 64));
    }
    bool okl = true;
    #pragma unroll
    for (int r=0;r<4;++r) okl = okl && (mnew[r] - mrow[r] <= 8.f);
    if (!__all(okl)){
      float scl[4];
      #pragma unroll
      for (int r=0;r<4;++r){
        scl[r] = __expf(mrow[r]-mnew[r]);
        mrow[r]=mnew[r];
        lrow[r]*=scl[r];
      }
      #pragma unroll
      for (int t12=0;t12<12;++t12){
        #pragma unroll
        for (int reg=0;reg<4;++reg) oacc[t12][reg]*=scl[reg];
      }
    }
    #pragma unroll
    for (int ct=0; ct<2; ++ct){
      #pragma unroll
      for (int reg=0; reg<4; ++reg){
        float p = __expf(sf[ct][reg]-mrow[reg]);
        lrow[reg]+=p;
        Ps[wave][4*lc+reg][ct*16+lr] = f2b(p);
      }
    }
    bf16x8 pa = *(const bf16x8*)(&Ps[wave][lr][lc*8]);
    #pragma unroll
    for (int t12=0; t12<12; ++t12){
      int vrow = t12*16 + lr;
      bf16x8 v0 = *(const bf16x8*)(&Vs[vrow][(lc ^ ((vrow>>1)&3))*8]);
      oacc[t12] = __builtin_amdgcn_mfma_f32_16x16x32_bf16(pa, v0, oacc[t12], 0,0,0);
    }
  }
  #pragma unroll
  for (int off=1; off<16; off<<=1){
    #pragma unroll
    for (int r=0;r<4;++r) lrow[r] += __shfl_xor(lrow[r], off, 64);
  }
  #pragma unroll
  for (int t12=0;t12<12;++t12){
    #pragma unroll
    for (int reg=0;reg<4;++reg){
      int rowloc = wave*16 + 4*lc + reg;
      PO[((size_t)wg*64 + rowloc)*DVH + t12*16 + lr] = f2b(oacc[t12][reg]);
    }
  }
  if (lr == 0){
    #pragma unroll
    for (int reg=0; reg<4; ++reg){
      int rowloc = wave*16 + 4*lc + reg;
      ML[(size_t)wg*64 + rowloc] = make_float2(mrow[reg], lrow[reg]);
    }
  }
}

// ---------------- combine KV-split partials -> Obuf bf16 [NSEQ][HDV] ----------------
__global__ __launch_bounds__(256) void k_comb(const bf16* __restrict__ PO, const float2* __restrict__ ML,
                                              bf16* __restrict__ Obuf){
  int i = blockIdx.x;
  int qtile = i>>6, rl = i&63;
  for (int c=threadIdx.x; c<HDV; c+=256){
    int h = c/DVH, d = c - h*DVH;
    int wg0 = qtile*8 + h, wg1 = 512 + wg0;
    float2 ml0 = ML[(size_t)wg0*64 + rl];
    float2 ml1 = ML[(size_t)wg1*64 + rl];
    float M = fmaxf(ml0.x, ml1.x);
    float w0 = __expf(ml0.x - M), w1 = __expf(ml1.x - M);
    float l = ml0.y*w0 + ml1.y*w1;
    float o = b2f(PO[((size_t)wg0*64 + rl)*DVH + d])*w0
            + b2f(PO[((size_t)wg1*64 + rl)*DVH + d])*w1;
    Obuf[(size_t)i*HDV + c] = f2b(o / l);
  }
}

extern "C" void kernel_launch(void* const* d_in, const int* in_sizes, int n_in,
                              void* d_out, int out_size, void* d_ws, size_t ws_size,
                              hipStream_t stream) {
  const float* x  = (const float*)d_in[0];
  const float* lg = (const float*)d_in[1];
  const float* lb = (const float*)d_in[2];
  const float* Wq = (const float*)d_in[3];
  const float* Wk = (const float*)d_in[4];
  const float* Wv = (const float*)d_in[5];
  const float* Wr = (const float*)d_in[6];
  const float* Wo = (const float*)d_in[7];
  const float* bo = (const float*)d_in[8];
  const float* cb = (const float*)d_in[9];
  const float* pb = (const float*)d_in[10];
  float* out = (float*)d_out;

  char* ws = (char*)d_ws;
  size_t off = 0;
  auto alloc = [&](size_t bytes)->void*{ void* p = ws + off; off += (bytes + 255) & ~(size_t)255; return p; };
  // persistent through k_attn:
  bf16* WoT  = (bf16*)alloc((size_t)DIMX*HDV*2);
  bf16* qph  = (bf16*)alloc((size_t)NSEQ*HDK*2);
  bf16* qpl  = (bf16*)alloc((size_t)NSEQ*HDK*2);
  bf16* kh   = (bf16*)alloc((size_t)NSEQ*HDK*2);   // d-chunk swizzled
  bf16* kl   = (bf16*)alloc((size_t)NSEQ*HDK*2);   // d-chunk swizzled
  bf16* vt   = (bf16*)alloc((size_t)HDV*NSEQ*2);   // kv-chunk swizzled
  float* ab  = (float*)alloc((size_t)NHEAD*NSEQ*34*4);
  bf16* Obuf = (bf16*)alloc((size_t)NSEQ*HDV*2);
  float2* ML = (float2*)alloc((size_t)KSPLIT*512*64*sizeof(float2));
  // scratch (dead before k_attn) — PO aliases it:
  char* scratch = (char*)alloc(0);
  bf16* xnh  = (bf16*)alloc((size_t)NSEQ*DIMX*2);
  bf16* xnl  = (bf16*)alloc((size_t)NSEQ*DIMX*2);
  bf16* v_rm = (bf16*)alloc((size_t)NSEQ*HDV*2);
  bf16* WqkT = (bf16*)alloc((size_t)1024*DIMX*2);
  bf16* WvT  = (bf16*)alloc((size_t)HDV*DIMX*2);
  bf16* PO   = (bf16*)scratch;   // KSPLIT*512*64*192*2 = 24 MB <= xnh+xnl
  (void)in_sizes; (void)n_in; (void)out_size; (void)ws_size;

  k_cvtT<<<dim3(HDK/32,  DIMX/32), 256, 0, stream>>>(Wq, WqkT, DIMX, HDK);
  k_cvtT<<<dim3(HDK/32,  DIMX/32), 256, 0, stream>>>(Wk, WqkT + (size_t)512*DIMX, DIMX, HDK);
  k_cvtT<<<dim3(HDV/32,  DIMX/32), 256, 0, stream>>>(Wv, WvT, DIMX, HDV);
  k_cvtT<<<dim3(DIMX/32, HDV/32),  256, 0, stream>>>(Wo, WoT, HDV, DIMX);
  k_ln<<<NSEQ, 256, 0, stream>>>(x, lg, lb, xnh, xnl);

  k_gemmqk<<<(NSEQ/128)*(1024/128), 256, 0, stream>>>(xnh, xnl, WqkT, qph, qpl, kh, kl, cb);
  k_gemm<0><<<(NSEQ/128)*(HDV/128), 256, 0, stream>>>(xnh, WvT, (void*)v_rm, nullptr, NSEQ, HDV, DIMX);

  k_abtab<<<NSEQ, 256, 0, stream>>>(qph, qpl, Wr, cb, pb, ab);
  k_T<<<dim3(HDV/64, NSEQ/64), 256, 0, stream>>>(v_rm, vt, NSEQ, HDV);

  k_attn<<<KSPLIT*512, 256, 0, stream>>>(qph, qpl, kh, kl, vt, ab, PO, ML);
  k_comb<<<NSEQ, 256, 0, stream>>>(PO, ML, Obuf);

  k_gemm<1><<<(NSEQ/128)*(DIMX/128), 256, 0, stream>>>(Obuf, WoT, (void*)out, bo, NSEQ, DIMX, HDV);
}